// Round 1
// baseline (565.222 us; speedup 1.0000x reference)
//
#include <hip/hip_runtime.h>
#include <math.h>

#define NBINS 182
#define NB 128   // batch

// ---------------------------------------------------------------------------
// Build M = F_dft @ C_dct (256x256 complex), in double, store fp32.
// M[j,w] = sum_k exp(-2*pi*i*j*k/256) * 2*cos(pi*(2w+1)k/512)
// ---------------------------------------------------------------------------
__global__ __launch_bounds__(256) void build_M(float* __restrict__ M_re,
                                               float* __restrict__ M_im) {
    __shared__ double ctab[1024];
    __shared__ double stab[1024];
    int t = threadIdx.x;
    for (int i = t; i < 1024; i += 256) {
        double a = 3.14159265358979323846 * (double)i / 512.0;
        ctab[i] = cos(a);
        stab[i] = sin(a);
    }
    __syncthreads();
    int j = blockIdx.x;   // frequency row
    int w = t;            // dct position col
    double re = 0.0, im = 0.0;
    int tw = 2 * w + 1;
    for (int k = 0; k < 256; ++k) {
        int e = (4 * j * k) & 1023;     // exp(-2pi i jk/256) -> angle pi*e/512
        int m = (tw * k) & 1023;        // cos(pi*(2w+1)k/512)
        double cw = 2.0 * ctab[m];
        re += ctab[e] * cw;
        im -= stab[e] * cw;
    }
    M_re[j * 256 + w] = (float)re;
    M_im[j * 256 + w] = (float)im;
}

// ---------------------------------------------------------------------------
// Radial bin helper: exact floor(sqrt(d2)) with integer fixup
// ---------------------------------------------------------------------------
__device__ __forceinline__ int radial_bin(int dx, int dy) {
    int d2 = dx * dx + dy * dy;
    int bin = (int)sqrtf((float)d2);
    while ((bin + 1) * (bin + 1) <= d2) ++bin;
    while (bin * bin > d2) --bin;
    return bin;
}

// ---------------------------------------------------------------------------
// nr[bin] = pixel count per radial bin (fftshifted grid)
// ---------------------------------------------------------------------------
__global__ __launch_bounds__(256) void count_nr(float* __restrict__ nr) {
    int i = blockIdx.x;      // row (shifted)
    int j = threadIdx.x;     // col (shifted)
    int bin = radial_bin(j - 128, i - 128);
    atomicAdd(&nr[bin], 1.0f);
}

// ---------------------------------------------------------------------------
// Stage 1: T[b] = G[b] @ M^T  (G = gray combine of x channels, done on load)
// T_re[b,h,j] = sum_w G[b,h,w]*M_re[j,w];  T_im likewise.
// Tile 64x64, 256 threads, 4x4 per thread, K-tile 16.
// ---------------------------------------------------------------------------
__global__ __launch_bounds__(256) void gemm1(const float* __restrict__ x,
                                             const float* __restrict__ M_re,
                                             const float* __restrict__ M_im,
                                             float* __restrict__ T_re,
                                             float* __restrict__ T_im) {
    __shared__ float As[16][68];
    __shared__ float Bre[16][68];
    __shared__ float Bim[16][68];
    int b = blockIdx.z;
    int row0 = blockIdx.y * 64;   // h tile
    int col0 = blockIdx.x * 64;   // j tile
    int t = threadIdx.x;
    int tx = t & 15, ty = t >> 4;
    int lr = t >> 2;          // 0..63: tile row for loads
    int lk = (t & 3) * 4;     // 0,4,8,12: k sub-offset for loads

    float accre[4][4] = {{0}};
    float accim[4][4] = {{0}};

    const float* x0 = x + (size_t)b * 3 * 65536;

    for (int kk = 0; kk < 256; kk += 16) {
        // A tile: gray of x, transposed into As[k][row]
        {
            const float* p = x0 + (row0 + lr) * 256 + kk + lk;
            float4 r = *(const float4*)(p);
            float4 g = *(const float4*)(p + 65536);
            float4 bb = *(const float4*)(p + 131072);
            As[lk + 0][lr] = 0.2989f * r.x + 0.587f * g.x + 0.114f * bb.x;
            As[lk + 1][lr] = 0.2989f * r.y + 0.587f * g.y + 0.114f * bb.y;
            As[lk + 2][lr] = 0.2989f * r.z + 0.587f * g.z + 0.114f * bb.z;
            As[lk + 3][lr] = 0.2989f * r.w + 0.587f * g.w + 0.114f * bb.w;
        }
        // B tiles: M rows (j), transposed into B[k][col]
        {
            const float* p = M_re + (col0 + lr) * 256 + kk + lk;
            float4 v = *(const float4*)p;
            Bre[lk + 0][lr] = v.x; Bre[lk + 1][lr] = v.y;
            Bre[lk + 2][lr] = v.z; Bre[lk + 3][lr] = v.w;
            const float* q = M_im + (col0 + lr) * 256 + kk + lk;
            float4 u = *(const float4*)q;
            Bim[lk + 0][lr] = u.x; Bim[lk + 1][lr] = u.y;
            Bim[lk + 2][lr] = u.z; Bim[lk + 3][lr] = u.w;
        }
        __syncthreads();
#pragma unroll
        for (int k = 0; k < 16; ++k) {
            float4 a4 = *(const float4*)&As[k][4 * ty];
            float4 br4 = *(const float4*)&Bre[k][4 * tx];
            float4 bi4 = *(const float4*)&Bim[k][4 * tx];
            float aa[4] = {a4.x, a4.y, a4.z, a4.w};
            float br[4] = {br4.x, br4.y, br4.z, br4.w};
            float bi[4] = {bi4.x, bi4.y, bi4.z, bi4.w};
#pragma unroll
            for (int i = 0; i < 4; ++i)
#pragma unroll
                for (int jj = 0; jj < 4; ++jj) {
                    accre[i][jj] = fmaf(aa[i], br[jj], accre[i][jj]);
                    accim[i][jj] = fmaf(aa[i], bi[jj], accim[i][jj]);
                }
        }
        __syncthreads();
    }
    size_t base = (size_t)b * 65536;
#pragma unroll
    for (int i = 0; i < 4; ++i) {
        int h = row0 + 4 * ty + i;
        float4 vre = {accre[i][0], accre[i][1], accre[i][2], accre[i][3]};
        float4 vim = {accim[i][0], accim[i][1], accim[i][2], accim[i][3]};
        *(float4*)&T_re[base + h * 256 + col0 + 4 * tx] = vre;
        *(float4*)&T_im[base + h * 256 + col0 + 4 * tx] = vim;
    }
}

// ---------------------------------------------------------------------------
// Stage 2: F[b] = M @ T[b] (complex), fused mag/fftshift/radial-bin epilogue.
// ---------------------------------------------------------------------------
__global__ __launch_bounds__(256) void gemm2(const float* __restrict__ M_re,
                                             const float* __restrict__ M_im,
                                             const float* __restrict__ T_re,
                                             const float* __restrict__ T_im,
                                             float* __restrict__ tbin) {
    __shared__ float Are[16][68];
    __shared__ float Aim[16][68];
    __shared__ float Bre[16][68];
    __shared__ float Bim[16][68];
    __shared__ float sbins[NBINS];
    int b = blockIdx.z;
    int u0 = blockIdx.y * 64;   // output freq row tile
    int j0 = blockIdx.x * 64;   // output freq col tile
    int t = threadIdx.x;
    int tx = t & 15, ty = t >> 4;
    int lr = t >> 2;          // A-load tile row
    int lk = (t & 3) * 4;     // A-load k sub-offset
    int bk = t >> 4;          // B-load k (0..15)
    int bc = (t & 15) * 4;    // B-load col

    for (int i = t; i < NBINS; i += 256) sbins[i] = 0.0f;

    float fre[4][4] = {{0}};
    float fim[4][4] = {{0}};
    size_t tb = (size_t)b * 65536;

    for (int kk = 0; kk < 256; kk += 16) {
        {
            const float* p = M_re + (u0 + lr) * 256 + kk + lk;
            float4 v = *(const float4*)p;
            Are[lk + 0][lr] = v.x; Are[lk + 1][lr] = v.y;
            Are[lk + 2][lr] = v.z; Are[lk + 3][lr] = v.w;
            const float* q = M_im + (u0 + lr) * 256 + kk + lk;
            float4 u = *(const float4*)q;
            Aim[lk + 0][lr] = u.x; Aim[lk + 1][lr] = u.y;
            Aim[lk + 2][lr] = u.z; Aim[lk + 3][lr] = u.w;
        }
        {
            const float* p = T_re + tb + (kk + bk) * 256 + j0 + bc;
            *(float4*)&Bre[bk][bc] = *(const float4*)p;
            const float* q = T_im + tb + (kk + bk) * 256 + j0 + bc;
            *(float4*)&Bim[bk][bc] = *(const float4*)q;
        }
        __syncthreads();
#pragma unroll
        for (int k = 0; k < 16; ++k) {
            float4 ar4 = *(const float4*)&Are[k][4 * ty];
            float4 ai4 = *(const float4*)&Aim[k][4 * ty];
            float4 br4 = *(const float4*)&Bre[k][4 * tx];
            float4 bi4 = *(const float4*)&Bim[k][4 * tx];
            float ar[4] = {ar4.x, ar4.y, ar4.z, ar4.w};
            float ai[4] = {ai4.x, ai4.y, ai4.z, ai4.w};
            float br[4] = {br4.x, br4.y, br4.z, br4.w};
            float bi[4] = {bi4.x, bi4.y, bi4.z, bi4.w};
#pragma unroll
            for (int i = 0; i < 4; ++i)
#pragma unroll
                for (int jj = 0; jj < 4; ++jj) {
                    fre[i][jj] = fmaf(ar[i], br[jj],
                                   fmaf(-ai[i], bi[jj], fre[i][jj]));
                    fim[i][jj] = fmaf(ar[i], bi[jj],
                                   fmaf(ai[i], br[jj], fim[i][jj]));
                }
        }
        __syncthreads();
    }

    // Epilogue: |F| -> log-mag -> fftshifted radial bin accumulation
#pragma unroll
    for (int i = 0; i < 4; ++i) {
        int u = u0 + 4 * ty + i;
        int dy = (u < 128) ? u : u - 256;
#pragma unroll
        for (int jj = 0; jj < 4; ++jj) {
            int v = j0 + 4 * tx + jj;
            int dx = (v < 128) ? v : v - 256;
            int bin = radial_bin(dx, dy);
            float re = fre[i][jj] + 1e-8f;
            float im = fim[i][jj] + 1e-8f;
            float mag = logf(sqrtf(re * re + im * im + 1e-10f) + 1e-10f);
            atomicAdd(&sbins[bin], mag);
        }
    }
    __syncthreads();
    for (int i = t; i < NBINS; i += 256) atomicAdd(&tbin[b * NBINS + i], sbins[i]);
}

// ---------------------------------------------------------------------------
// Finalize: prof = tbin/nr, slice [1:180), min-max normalize, dot with w.
// ---------------------------------------------------------------------------
__global__ __launch_bounds__(192) void finalize(const float* __restrict__ tbin,
                                                const float* __restrict__ nr,
                                                const float* __restrict__ w,
                                                const float* __restrict__ bias,
                                                float* __restrict__ out) {
    __shared__ float prof[NBINS];
    __shared__ float smn, smx, ssum;
    int b = blockIdx.x;
    int t = threadIdx.x;
    if (t < NBINS) prof[t] = tbin[b * NBINS + t] / (nr[t] + 1e-10f);
    __syncthreads();
    if (t == 0) {
        float mn = prof[1], mx = prof[1];
        for (int i = 2; i <= 179; ++i) {
            float p = prof[i];
            mn = fminf(mn, p);
            mx = fmaxf(mx, p);
        }
        smn = mn; smx = mx; ssum = 0.0f;
    }
    __syncthreads();
    if (t < 90) {
        float denom = smx - smn;
        float v = (prof[90 + t] - smn) / denom;
        if (v != v) v = 0.0f;   // NaN -> 0
        atomicAdd(&ssum, v * w[t]);
    }
    __syncthreads();
    if (t == 0) out[b] = ssum + bias[0];
}

// ---------------------------------------------------------------------------
extern "C" void kernel_launch(void* const* d_in, const int* in_sizes, int n_in,
                              void* d_out, int out_size, void* d_ws, size_t ws_size,
                              hipStream_t stream) {
    const float* x = (const float*)d_in[0];     // (128,3,256,256)
    const float* w = (const float*)d_in[1];     // (1,90)
    const float* bias = (const float*)d_in[2];  // (1,)
    float* out = (float*)d_out;                 // (128,1)

    float* ws = (float*)d_ws;
    float* M_re = ws;
    float* M_im = ws + 65536;
    float* T_re = ws + 131072;
    float* T_im = T_re + (size_t)NB * 65536;
    float* tbin = T_im + (size_t)NB * 65536;
    float* nr = tbin + NB * NBINS;

    hipMemsetAsync(tbin, 0, (NB * NBINS + NBINS) * sizeof(float), stream);

    build_M<<<256, 256, 0, stream>>>(M_re, M_im);
    count_nr<<<256, 256, 0, stream>>>(nr);

    dim3 g(4, 4, NB);
    gemm1<<<g, 256, 0, stream>>>(x, M_re, M_im, T_re, T_im);
    gemm2<<<g, 256, 0, stream>>>(M_re, M_im, T_re, T_im, tbin);

    finalize<<<NB, 192, 0, stream>>>(tbin, nr, w, bias, out);
}

// Round 2
// 484.334 us; speedup vs baseline: 1.1670x; 1.1670x over previous
//
#include <hip/hip_runtime.h>
#include <math.h>

#define NBINS 182
#define NB 128   // batch

// ---------------------------------------------------------------------------
// Build M = F_dft @ C_dct (256x256 complex), in double, store fp32.
// M[j,w] = sum_k exp(-2*pi*i*j*k/256) * 2*cos(pi*(2w+1)k/512)
// Note M[256-j,:] = conj(M[j,:]) and M[128,:] is real.
// ---------------------------------------------------------------------------
__global__ __launch_bounds__(256) void build_M(float* __restrict__ M_re,
                                               float* __restrict__ M_im) {
    __shared__ double ctab[1024];
    __shared__ double stab[1024];
    int t = threadIdx.x;
    for (int i = t; i < 1024; i += 256) {
        double a = 3.14159265358979323846 * (double)i / 512.0;
        ctab[i] = cos(a);
        stab[i] = sin(a);
    }
    __syncthreads();
    int j = blockIdx.x;   // frequency row
    int w = t;            // dct position col
    double re = 0.0, im = 0.0;
    int tw = 2 * w + 1;
    for (int k = 0; k < 256; ++k) {
        int e = (4 * j * k) & 1023;     // exp(-2pi i jk/256) -> angle pi*e/512
        int m = (tw * k) & 1023;        // cos(pi*(2w+1)k/512)
        double cw = 2.0 * ctab[m];
        re += ctab[e] * cw;
        im -= stab[e] * cw;
    }
    M_re[j * 256 + w] = (float)re;
    M_im[j * 256 + w] = (float)im;
}

// ---------------------------------------------------------------------------
// Radial bin helper: exact floor(sqrt(d2)) with integer fixup
// ---------------------------------------------------------------------------
__device__ __forceinline__ int radial_bin(int dx, int dy) {
    int d2 = dx * dx + dy * dy;
    int bin = (int)sqrtf((float)d2);
    while ((bin + 1) * (bin + 1) <= d2) ++bin;
    while (bin * bin > d2) --bin;
    return bin;
}

// ---------------------------------------------------------------------------
// nr[bin]: single block, LDS atomics (was 65536 contended global atomics)
// ---------------------------------------------------------------------------
__global__ __launch_bounds__(256) void count_nr(float* __restrict__ nr) {
    __shared__ float s[NBINS];
    int t = threadIdx.x;
    if (t < NBINS) s[t] = 0.0f;
    __syncthreads();
    for (int i = 0; i < 256; ++i) {
        int bin = radial_bin(t - 128, i - 128);
        atomicAdd(&s[bin], 1.0f);
    }
    __syncthreads();
    if (t < NBINS) nr[t] = s[t];
}

// ---------------------------------------------------------------------------
// Stage 1: T[b] = G[b] @ M^T, columns j = 0..127 only (Hermitian halving).
// ---------------------------------------------------------------------------
__global__ __launch_bounds__(256) void gemm1(const float* __restrict__ x,
                                             const float* __restrict__ M_re,
                                             const float* __restrict__ M_im,
                                             float* __restrict__ T_re,
                                             float* __restrict__ T_im) {
    __shared__ float As[16][68];
    __shared__ float Bre[16][68];
    __shared__ float Bim[16][68];
    int b = blockIdx.z;
    int row0 = blockIdx.y * 64;   // h tile
    int col0 = blockIdx.x * 64;   // j tile (0 or 64)
    int t = threadIdx.x;
    int tx = t & 15, ty = t >> 4;
    int lr = t >> 2;          // 0..63: tile row for loads
    int lk = (t & 3) * 4;     // 0,4,8,12: k sub-offset for loads

    float accre[4][4] = {{0}};
    float accim[4][4] = {{0}};

    const float* x0 = x + (size_t)b * 3 * 65536;

    for (int kk = 0; kk < 256; kk += 16) {
        {
            const float* p = x0 + (row0 + lr) * 256 + kk + lk;
            float4 r = *(const float4*)(p);
            float4 g = *(const float4*)(p + 65536);
            float4 bb = *(const float4*)(p + 131072);
            As[lk + 0][lr] = 0.2989f * r.x + 0.587f * g.x + 0.114f * bb.x;
            As[lk + 1][lr] = 0.2989f * r.y + 0.587f * g.y + 0.114f * bb.y;
            As[lk + 2][lr] = 0.2989f * r.z + 0.587f * g.z + 0.114f * bb.z;
            As[lk + 3][lr] = 0.2989f * r.w + 0.587f * g.w + 0.114f * bb.w;
        }
        {
            const float* p = M_re + (col0 + lr) * 256 + kk + lk;
            float4 v = *(const float4*)p;
            Bre[lk + 0][lr] = v.x; Bre[lk + 1][lr] = v.y;
            Bre[lk + 2][lr] = v.z; Bre[lk + 3][lr] = v.w;
            const float* q = M_im + (col0 + lr) * 256 + kk + lk;
            float4 u = *(const float4*)q;
            Bim[lk + 0][lr] = u.x; Bim[lk + 1][lr] = u.y;
            Bim[lk + 2][lr] = u.z; Bim[lk + 3][lr] = u.w;
        }
        __syncthreads();
#pragma unroll
        for (int k = 0; k < 16; ++k) {
            float4 a4 = *(const float4*)&As[k][4 * ty];
            float4 br4 = *(const float4*)&Bre[k][4 * tx];
            float4 bi4 = *(const float4*)&Bim[k][4 * tx];
            float aa[4] = {a4.x, a4.y, a4.z, a4.w};
            float br[4] = {br4.x, br4.y, br4.z, br4.w};
            float bi[4] = {bi4.x, bi4.y, bi4.z, bi4.w};
#pragma unroll
            for (int i = 0; i < 4; ++i)
#pragma unroll
                for (int jj = 0; jj < 4; ++jj) {
                    accre[i][jj] = fmaf(aa[i], br[jj], accre[i][jj]);
                    accim[i][jj] = fmaf(aa[i], bi[jj], accim[i][jj]);
                }
        }
        __syncthreads();
    }
    size_t base = (size_t)b * 65536;
#pragma unroll
    for (int i = 0; i < 4; ++i) {
        int h = row0 + 4 * ty + i;
        float4 vre = {accre[i][0], accre[i][1], accre[i][2], accre[i][3]};
        float4 vim = {accim[i][0], accim[i][1], accim[i][2], accim[i][3]};
        *(float4*)&T_re[base + h * 256 + col0 + 4 * tx] = vre;
        *(float4*)&T_im[base + h * 256 + col0 + 4 * tx] = vim;
    }
}

// ---------------------------------------------------------------------------
// Column 128 of T: T[h,128] = sum_w G[h,w]*M_re[128,w]  (real; M[128,:] real).
// One block per batch; wave-per-row, coalesced over w.
// ---------------------------------------------------------------------------
__global__ __launch_bounds__(256) void col128(const float* __restrict__ x,
                                              const float* __restrict__ M_re,
                                              float* __restrict__ T_re,
                                              float* __restrict__ T_im) {
    __shared__ float sM[256];
    int b = blockIdx.x;
    int t = threadIdx.x;
    sM[t] = M_re[128 * 256 + t];
    __syncthreads();
    int lane = t & 63, wv = t >> 6;
    const float* x0 = x + (size_t)b * 3 * 65536;
    size_t tb = (size_t)b * 65536;
    for (int h = wv; h < 256; h += 4) {
        float acc = 0.0f;
        const float* pr = x0 + h * 256;
#pragma unroll
        for (int s = 0; s < 4; ++s) {
            int w = lane + 64 * s;
            float g = 0.2989f * pr[w] + 0.587f * pr[w + 65536]
                    + 0.114f * pr[w + 131072];
            acc = fmaf(g, sM[w], acc);
        }
#pragma unroll
        for (int off = 32; off > 0; off >>= 1)
            acc += __shfl_xor(acc, off, 64);
        if (lane == 0) {
            T_re[tb + h * 256 + 128] = acc;
            T_im[tb + h * 256 + 128] = 0.0f;
        }
    }
}

// ---------------------------------------------------------------------------
// Stage 2: F = M @ T, rows u = 0..127 only (Hermitian: mag[u,v]=mag[-u,-v]).
// j tiles >= 128 reconstruct B from conj(T[:,256-j]).
// Fused mag/fftshift/radial-bin epilogue with row weight (u==0 ? 1 : 2).
// ---------------------------------------------------------------------------
__global__ __launch_bounds__(256) void gemm2(const float* __restrict__ M_re,
                                             const float* __restrict__ M_im,
                                             const float* __restrict__ T_re,
                                             const float* __restrict__ T_im,
                                             float* __restrict__ tbin) {
    __shared__ float Are[16][68];
    __shared__ float Aim[16][68];
    __shared__ float Bre[16][68];
    __shared__ float Bim[16][68];
    __shared__ float sbins[NBINS];
    int b = blockIdx.z;
    int u0 = blockIdx.y * 64;   // 0 or 64
    int j0 = blockIdx.x * 64;   // 0,64,128,192
    int t = threadIdx.x;
    int tx = t & 15, ty = t >> 4;
    int lr = t >> 2;
    int lk = (t & 3) * 4;
    int bk = t >> 4;          // B-load k (0..15)
    int bc = (t & 15) * 4;    // B-load col

    for (int i = t; i < NBINS; i += 256) sbins[i] = 0.0f;

    float fre[4][4] = {{0}};
    float fim[4][4] = {{0}};
    size_t tb = (size_t)b * 65536;

    for (int kk = 0; kk < 256; kk += 16) {
        {
            const float* p = M_re + (u0 + lr) * 256 + kk + lk;
            float4 v = *(const float4*)p;
            Are[lk + 0][lr] = v.x; Are[lk + 1][lr] = v.y;
            Are[lk + 2][lr] = v.z; Are[lk + 3][lr] = v.w;
            const float* q = M_im + (u0 + lr) * 256 + kk + lk;
            float4 u = *(const float4*)q;
            Aim[lk + 0][lr] = u.x; Aim[lk + 1][lr] = u.y;
            Aim[lk + 2][lr] = u.z; Aim[lk + 3][lr] = u.w;
        }
        if (j0 < 128) {
            const float* p = T_re + tb + (kk + bk) * 256 + j0 + bc;
            *(float4*)&Bre[bk][bc] = *(const float4*)p;
            const float* q = T_im + tb + (kk + bk) * 256 + j0 + bc;
            *(float4*)&Bim[bk][bc] = *(const float4*)q;
        } else {
            size_t rowb = tb + (size_t)(kk + bk) * 256;
#pragma unroll
            for (int i = 0; i < 4; ++i) {
                int src = 256 - (j0 + bc + i);   // in 1..128
                Bre[bk][bc + i] = T_re[rowb + src];
                Bim[bk][bc + i] = -T_im[rowb + src];
            }
        }
        __syncthreads();
#pragma unroll
        for (int k = 0; k < 16; ++k) {
            float4 ar4 = *(const float4*)&Are[k][4 * ty];
            float4 ai4 = *(const float4*)&Aim[k][4 * ty];
            float4 br4 = *(const float4*)&Bre[k][4 * tx];
            float4 bi4 = *(const float4*)&Bim[k][4 * tx];
            float ar[4] = {ar4.x, ar4.y, ar4.z, ar4.w};
            float ai[4] = {ai4.x, ai4.y, ai4.z, ai4.w};
            float br[4] = {br4.x, br4.y, br4.z, br4.w};
            float bi[4] = {bi4.x, bi4.y, bi4.z, bi4.w};
#pragma unroll
            for (int i = 0; i < 4; ++i)
#pragma unroll
                for (int jj = 0; jj < 4; ++jj) {
                    fre[i][jj] = fmaf(ar[i], br[jj],
                                   fmaf(-ai[i], bi[jj], fre[i][jj]));
                    fim[i][jj] = fmaf(ar[i], bi[jj],
                                   fmaf(ai[i], br[jj], fim[i][jj]));
                }
        }
        __syncthreads();
    }

#pragma unroll
    for (int i = 0; i < 4; ++i) {
        int u = u0 + 4 * ty + i;          // 0..127
        int dy = (u < 128) ? u : u - 256;
        float wrow = (u == 0) ? 1.0f : 2.0f;
#pragma unroll
        for (int jj = 0; jj < 4; ++jj) {
            int v = j0 + 4 * tx + jj;
            int dx = (v < 128) ? v : v - 256;
            int bin = radial_bin(dx, dy);
            float re = fre[i][jj] + 1e-8f;
            float im = fim[i][jj] + 1e-8f;
            float mag = logf(sqrtf(re * re + im * im + 1e-10f) + 1e-10f);
            atomicAdd(&sbins[bin], wrow * mag);
        }
    }
    __syncthreads();
    for (int i = t; i < NBINS; i += 256) atomicAdd(&tbin[b * NBINS + i], sbins[i]);
}

// ---------------------------------------------------------------------------
// Row 128 of F: F[128,j] = sum_h M_re[128,h]*T[h,j], j = 0..128.
// Weights: j=0,128 -> 1; j=1..127 -> 2 (pairs (128,v)<->(128,256-v)).
// ---------------------------------------------------------------------------
__global__ __launch_bounds__(256) void row128(const float* __restrict__ M_re,
                                              const float* __restrict__ T_re,
                                              const float* __restrict__ T_im,
                                              float* __restrict__ tbin) {
    __shared__ float sM[256];
    int b = blockIdx.x;
    int t = threadIdx.x;
    sM[t] = M_re[128 * 256 + t];
    __syncthreads();
    if (t > 128) return;
    size_t tb = (size_t)b * 65536;
    float re = 0.0f, im = 0.0f;
    for (int h = 0; h < 256; h += 4) {
#pragma unroll
        for (int q = 0; q < 4; ++q) {
            float m = sM[h + q];
            re = fmaf(m, T_re[tb + (size_t)(h + q) * 256 + t], re);
            im = fmaf(m, T_im[tb + (size_t)(h + q) * 256 + t], im);
        }
    }
    re += 1e-8f; im += 1e-8f;
    float mag = logf(sqrtf(re * re + im * im + 1e-10f) + 1e-10f);
    float wj = (t == 0 || t == 128) ? 1.0f : 2.0f;
    int dx = (t < 128) ? t : t - 256;    // t=128 -> -128
    int bin = radial_bin(dx, -128);
    atomicAdd(&tbin[b * NBINS + bin], wj * mag);
}

// ---------------------------------------------------------------------------
// Finalize: prof = tbin/nr, min-max over bins 1..179, dot bins 90..179 with w.
// ---------------------------------------------------------------------------
__global__ __launch_bounds__(192) void finalize(const float* __restrict__ tbin,
                                                const float* __restrict__ nr,
                                                const float* __restrict__ w,
                                                const float* __restrict__ bias,
                                                float* __restrict__ out) {
    __shared__ float prof[NBINS];
    __shared__ float smn, smx, ssum;
    int b = blockIdx.x;
    int t = threadIdx.x;
    if (t < NBINS) prof[t] = tbin[b * NBINS + t] / (nr[t] + 1e-10f);
    __syncthreads();
    if (t == 0) {
        float mn = prof[1], mx = prof[1];
        for (int i = 2; i <= 179; ++i) {
            float p = prof[i];
            mn = fminf(mn, p);
            mx = fmaxf(mx, p);
        }
        smn = mn; smx = mx; ssum = 0.0f;
    }
    __syncthreads();
    if (t < 90) {
        float denom = smx - smn;
        float v = (prof[90 + t] - smn) / denom;
        if (v != v) v = 0.0f;   // NaN -> 0
        atomicAdd(&ssum, v * w[t]);
    }
    __syncthreads();
    if (t == 0) out[b] = ssum + bias[0];
}

// ---------------------------------------------------------------------------
extern "C" void kernel_launch(void* const* d_in, const int* in_sizes, int n_in,
                              void* d_out, int out_size, void* d_ws, size_t ws_size,
                              hipStream_t stream) {
    const float* x = (const float*)d_in[0];     // (128,3,256,256)
    const float* w = (const float*)d_in[1];     // (1,90)
    const float* bias = (const float*)d_in[2];  // (1,)
    float* out = (float*)d_out;                 // (128,1)

    float* ws = (float*)d_ws;
    float* M_re = ws;
    float* M_im = ws + 65536;
    float* T_re = ws + 131072;
    float* T_im = T_re + (size_t)NB * 65536;
    float* tbin = T_im + (size_t)NB * 65536;
    float* nr = tbin + NB * NBINS;

    hipMemsetAsync(tbin, 0, NB * NBINS * sizeof(float), stream);

    build_M<<<256, 256, 0, stream>>>(M_re, M_im);
    count_nr<<<1, 256, 0, stream>>>(nr);

    gemm1<<<dim3(2, 4, NB), 256, 0, stream>>>(x, M_re, M_im, T_re, T_im);
    col128<<<NB, 256, 0, stream>>>(x, M_re, T_re, T_im);
    gemm2<<<dim3(4, 2, NB), 256, 0, stream>>>(M_re, M_im, T_re, T_im, tbin);
    row128<<<NB, 256, 0, stream>>>(M_re, T_re, T_im, tbin);

    finalize<<<NB, 192, 0, stream>>>(tbin, nr, w, bias, out);
}

// Round 3
// 332.913 us; speedup vs baseline: 1.6978x; 1.4548x over previous
//
#include <hip/hip_runtime.h>
#include <math.h>

#define NBINS 182
#define NB 128   // batch

typedef unsigned short u16;
typedef __attribute__((ext_vector_type(8))) short short8;   // 8 bf16 (4 VGPRs)
typedef __attribute__((ext_vector_type(4))) float f32x4;    // MFMA accumulator

__device__ __forceinline__ u16 f2bf(float f) {
    union { float f; unsigned u; } v; v.f = f;
    unsigned r = v.u + 0x7FFF + ((v.u >> 16) & 1);   // RNE
    return (u16)(r >> 16);
}
__device__ __forceinline__ float bf2f(u16 u) {
    union { unsigned u; float f; } v; v.u = ((unsigned)u) << 16;
    return v.f;
}
__device__ __forceinline__ short8 negbf(short8 v) {
    short8 r;
#pragma unroll
    for (int i = 0; i < 8; ++i) r[i] = v[i] ^ (short)0x8000;
    return r;
}

// ---------------------------------------------------------------------------
// Build M = F_dft @ C_dct (256x256 complex), fp64 accum -> fp32 + bf16 copies.
// A1 (512x256 bf16): rows 0..255 = M_re, rows 256..511 = M_im.
// ---------------------------------------------------------------------------
__global__ __launch_bounds__(256) void build_M(float* __restrict__ M_re,
                                               float* __restrict__ M_im,
                                               u16* __restrict__ A1) {
    __shared__ double ctab[1024];
    __shared__ double stab[1024];
    int t = threadIdx.x;
    for (int i = t; i < 1024; i += 256) {
        double a = 3.14159265358979323846 * (double)i / 512.0;
        ctab[i] = cos(a);
        stab[i] = sin(a);
    }
    __syncthreads();
    int j = blockIdx.x;
    int w = t;
    double re = 0.0, im = 0.0;
    int tw = 2 * w + 1;
    for (int k = 0; k < 256; ++k) {
        int e = (4 * j * k) & 1023;
        int m = (tw * k) & 1023;
        double cw = 2.0 * ctab[m];
        re += ctab[e] * cw;
        im -= stab[e] * cw;
    }
    M_re[j * 256 + w] = (float)re;
    M_im[j * 256 + w] = (float)im;
    A1[j * 256 + w] = f2bf((float)re);
    A1[(j + 256) * 256 + w] = f2bf((float)im);
}

// ---------------------------------------------------------------------------
__device__ __forceinline__ int radial_bin(int dx, int dy) {
    int d2 = dx * dx + dy * dy;
    int bin = (int)sqrtf((float)d2);
    while ((bin + 1) * (bin + 1) <= d2) ++bin;
    while (bin * bin > d2) --bin;
    return bin;
}

__global__ __launch_bounds__(256) void count_nr(float* __restrict__ nr) {
    __shared__ float s[NBINS];
    int t = threadIdx.x;
    if (t < NBINS) s[t] = 0.0f;
    __syncthreads();
    for (int i = 0; i < 256; ++i) {
        int bin = radial_bin(t - 128, i - 128);
        atomicAdd(&s[bin], 1.0f);
    }
    __syncthreads();
    if (t < NBINS) nr[t] = s[t];
}

// ---------------------------------------------------------------------------
// Gray conversion: G[b][h][w] = luma(x), bf16.
// ---------------------------------------------------------------------------
__global__ __launch_bounds__(256) void gray_k(const float* __restrict__ x,
                                              u16* __restrict__ G) {
    int idx = (blockIdx.x * 256 + threadIdx.x) * 4;   // 4 pixels; 8388608 total
    int b = idx >> 16;
    int rem = idx & 65535;
    const float* p = x + (size_t)b * 196608 + rem;
    float4 r = *(const float4*)p;
    float4 g = *(const float4*)(p + 65536);
    float4 bl = *(const float4*)(p + 131072);
    float g0 = 0.2989f * r.x + 0.587f * g.x + 0.114f * bl.x;
    float g1 = 0.2989f * r.y + 0.587f * g.y + 0.114f * bl.y;
    float g2 = 0.2989f * r.z + 0.587f * g.z + 0.114f * bl.z;
    float g3 = 0.2989f * r.w + 0.587f * g.w + 0.114f * bl.w;
    uint2 o;
    o.x = (unsigned)f2bf(g0) | ((unsigned)f2bf(g1) << 16);
    o.y = (unsigned)f2bf(g2) | ((unsigned)f2bf(g3) << 16);
    *(uint2*)(G + idx) = o;
}

// ---------------------------------------------------------------------------
// Stage 1 (MFMA): C[r][h] = sum_w A1[r,w] * G[b,h,w]   (gemm_bt)
// r in [0,512): r<256 -> Tt_re row r, else Tt_im row r-256. Output bf16.
// Block: 128x128 tile, 256 thr, wave = 64x64 (4x4 of 16x16x32). K=256, BK=32.
// ---------------------------------------------------------------------------
__global__ __launch_bounds__(256) void s1(const u16* __restrict__ A1,
                                          const u16* __restrict__ G,
                                          u16* __restrict__ Tt_re,
                                          u16* __restrict__ Tt_im) {
    __shared__ u16 As[128 * 40];   // row stride 40 (16B-aligned, conflict-free)
    __shared__ u16 Bs[128 * 40];
    int b = blockIdx.z;
    int r0 = blockIdx.y * 128;    // 0,128,256,384
    int h0 = blockIdx.x * 128;    // 0,128
    int t = threadIdx.x;
    int lane = t & 63, wv = t >> 6;
    int wr = (wv >> 1) * 64;      // wave row origin in block
    int wc = (wv & 1) * 64;       // wave col origin
    int fr = lane & 15;
    int fk = (lane >> 4) << 3;    // 0,8,16,24

    f32x4 acc[4][4];
#pragma unroll
    for (int i = 0; i < 4; ++i)
#pragma unroll
        for (int j = 0; j < 4; ++j) acc[i][j] = (f32x4){0.f, 0.f, 0.f, 0.f};

    const u16* Ap = A1 + (size_t)r0 * 256;
    const u16* Gp = G + (size_t)b * 65536 + (size_t)h0 * 256;

    for (int kk = 0; kk < 256; kk += 32) {
#pragma unroll
        for (int c = t; c < 512; c += 256) {   // 128 rows x 4 chunks of 8 bf16
            int row = c >> 2, off = (c & 3) << 3;
            *(uint4*)&As[row * 40 + off] =
                *(const uint4*)(Ap + (size_t)row * 256 + kk + off);
            *(uint4*)&Bs[row * 40 + off] =
                *(const uint4*)(Gp + (size_t)row * 256 + kk + off);
        }
        __syncthreads();
        short8 af[4], bfr[4];
#pragma unroll
        for (int i = 0; i < 4; ++i)
            af[i] = *(const short8*)&As[(wr + i * 16 + fr) * 40 + fk];
#pragma unroll
        for (int j = 0; j < 4; ++j)
            bfr[j] = *(const short8*)&Bs[(wc + j * 16 + fr) * 40 + fk];
#pragma unroll
        for (int i = 0; i < 4; ++i)
#pragma unroll
            for (int j = 0; j < 4; ++j)
                acc[i][j] = __builtin_amdgcn_mfma_f32_16x16x32_bf16(
                    af[i], bfr[j], acc[i][j], 0, 0, 0);
        __syncthreads();
    }

    u16* dst = ((r0 < 256) ? Tt_re : Tt_im) + (size_t)b * 65536
             + (size_t)(r0 & 255) * 256;
    int rq = (lane >> 4) << 2;
#pragma unroll
    for (int i = 0; i < 4; ++i)
#pragma unroll
        for (int j = 0; j < 4; ++j) {
            int col = h0 + wc + j * 16 + fr;
#pragma unroll
            for (int reg = 0; reg < 4; ++reg) {
                int row = wr + i * 16 + rq + reg;
                dst[(size_t)row * 256 + col] = f2bf(acc[i][j][reg]);
            }
        }
}

// ---------------------------------------------------------------------------
// Stage 2 (MFMA, complex): F[u][j] = sum_h (M_re+iM_im)[u,h] * Tt[j,h]
// u in [0,128) (Hermitian, weight 2 for u>0), j in [0,256).
// Block: 64x64 tile, 4 waves of 32x32 (2x2 of 16x16x32, re+im accumulators).
// Fused log-mag / fftshift / radial-bin epilogue.
// ---------------------------------------------------------------------------
__global__ __launch_bounds__(256) void s2(const u16* __restrict__ A1,
                                          const u16* __restrict__ Tt_re,
                                          const u16* __restrict__ Tt_im,
                                          float* __restrict__ tbin) {
    __shared__ u16 Ar[64 * 40], Ai[64 * 40], Br[64 * 40], Bi[64 * 40];
    __shared__ float sbins[NBINS];
    int b = blockIdx.z;
    int u0 = blockIdx.y * 64;    // 0,64
    int j0 = blockIdx.x * 64;    // 0,64,128,192
    int t = threadIdx.x;
    int lane = t & 63, wv = t >> 6;
    int wu = (wv >> 1) * 32;
    int wj = (wv & 1) * 32;
    int fr = lane & 15;
    int fk = (lane >> 4) << 3;

    for (int i = t; i < NBINS; i += 256) sbins[i] = 0.0f;

    f32x4 accr[2][2], acci[2][2];
#pragma unroll
    for (int i = 0; i < 2; ++i)
#pragma unroll
        for (int j = 0; j < 2; ++j) {
            accr[i][j] = (f32x4){0.f, 0.f, 0.f, 0.f};
            acci[i][j] = (f32x4){0.f, 0.f, 0.f, 0.f};
        }

    const u16* Apr = A1 + (size_t)u0 * 256;            // M_re rows u
    const u16* Api = A1 + (size_t)(256 + u0) * 256;    // M_im rows u
    const u16* Tr = Tt_re + (size_t)b * 65536 + (size_t)j0 * 256;
    const u16* Ti = Tt_im + (size_t)b * 65536 + (size_t)j0 * 256;

    int lrow = t >> 2, loff = (t & 3) << 3;   // 64 rows x 4 chunks

    for (int kk = 0; kk < 256; kk += 32) {
        *(uint4*)&Ar[lrow * 40 + loff] =
            *(const uint4*)(Apr + (size_t)lrow * 256 + kk + loff);
        *(uint4*)&Ai[lrow * 40 + loff] =
            *(const uint4*)(Api + (size_t)lrow * 256 + kk + loff);
        *(uint4*)&Br[lrow * 40 + loff] =
            *(const uint4*)(Tr + (size_t)lrow * 256 + kk + loff);
        *(uint4*)&Bi[lrow * 40 + loff] =
            *(const uint4*)(Ti + (size_t)lrow * 256 + kk + loff);
        __syncthreads();
        short8 arf[2], aif[2], naif[2], brf[2], bif[2];
#pragma unroll
        for (int i = 0; i < 2; ++i) {
            arf[i] = *(const short8*)&Ar[(wu + i * 16 + fr) * 40 + fk];
            aif[i] = *(const short8*)&Ai[(wu + i * 16 + fr) * 40 + fk];
            naif[i] = negbf(aif[i]);
        }
#pragma unroll
        for (int j = 0; j < 2; ++j) {
            brf[j] = *(const short8*)&Br[(wj + j * 16 + fr) * 40 + fk];
            bif[j] = *(const short8*)&Bi[(wj + j * 16 + fr) * 40 + fk];
        }
#pragma unroll
        for (int i = 0; i < 2; ++i)
#pragma unroll
            for (int j = 0; j < 2; ++j) {
                accr[i][j] = __builtin_amdgcn_mfma_f32_16x16x32_bf16(
                    arf[i], brf[j], accr[i][j], 0, 0, 0);
                accr[i][j] = __builtin_amdgcn_mfma_f32_16x16x32_bf16(
                    naif[i], bif[j], accr[i][j], 0, 0, 0);
                acci[i][j] = __builtin_amdgcn_mfma_f32_16x16x32_bf16(
                    arf[i], bif[j], acci[i][j], 0, 0, 0);
                acci[i][j] = __builtin_amdgcn_mfma_f32_16x16x32_bf16(
                    aif[i], brf[j], acci[i][j], 0, 0, 0);
            }
        __syncthreads();
    }

    int rq = (lane >> 4) << 2;
#pragma unroll
    for (int i = 0; i < 2; ++i)
#pragma unroll
        for (int j = 0; j < 2; ++j) {
            int v = j0 + wj + j * 16 + fr;
            int dx = (v < 128) ? v : v - 256;
#pragma unroll
            for (int reg = 0; reg < 4; ++reg) {
                int u = u0 + wu + i * 16 + rq + reg;   // 0..127
                int dy = u;
                float wrow = (u == 0) ? 1.0f : 2.0f;
                int bin = radial_bin(dx, dy);
                float re = accr[i][j][reg] + 1e-8f;
                float im = acci[i][j][reg] + 1e-8f;
                float mag = logf(sqrtf(re * re + im * im + 1e-10f) + 1e-10f);
                atomicAdd(&sbins[bin], wrow * mag);
            }
        }
    __syncthreads();
    for (int i = t; i < NBINS; i += 256)
        atomicAdd(&tbin[b * NBINS + i], sbins[i]);
}

// ---------------------------------------------------------------------------
// Row 128 of F: F[128,j] = sum_h M_re[128,h] * Tt[j,h], j = 0..128.
// ---------------------------------------------------------------------------
__global__ __launch_bounds__(256) void row128(const float* __restrict__ M_re,
                                              const u16* __restrict__ Tt_re,
                                              const u16* __restrict__ Tt_im,
                                              float* __restrict__ tbin) {
    __shared__ float sM[256];
    int b = blockIdx.x;
    int t = threadIdx.x;
    sM[t] = M_re[128 * 256 + t];
    __syncthreads();
    if (t > 128) return;
    const u16* pr = Tt_re + (size_t)b * 65536 + (size_t)t * 256;
    const u16* pi = Tt_im + (size_t)b * 65536 + (size_t)t * 256;
    float re = 0.0f, im = 0.0f;
    for (int h = 0; h < 256; h += 8) {
        uint4 vr = *(const uint4*)(pr + h);
        uint4 vi = *(const uint4*)(pi + h);
        unsigned wr[4] = {vr.x, vr.y, vr.z, vr.w};
        unsigned wi[4] = {vi.x, vi.y, vi.z, vi.w};
#pragma unroll
        for (int q = 0; q < 4; ++q) {
            re = fmaf(sM[h + 2 * q], bf2f((u16)(wr[q] & 0xffff)), re);
            re = fmaf(sM[h + 2 * q + 1], bf2f((u16)(wr[q] >> 16)), re);
            im = fmaf(sM[h + 2 * q], bf2f((u16)(wi[q] & 0xffff)), im);
            im = fmaf(sM[h + 2 * q + 1], bf2f((u16)(wi[q] >> 16)), im);
        }
    }
    re += 1e-8f; im += 1e-8f;
    float mag = logf(sqrtf(re * re + im * im + 1e-10f) + 1e-10f);
    float wj = (t == 0 || t == 128) ? 1.0f : 2.0f;
    int dx = (t < 128) ? t : t - 256;
    int bin = radial_bin(dx, -128);
    atomicAdd(&tbin[b * NBINS + bin], wj * mag);
}

// ---------------------------------------------------------------------------
__global__ __launch_bounds__(192) void finalize(const float* __restrict__ tbin,
                                                const float* __restrict__ nr,
                                                const float* __restrict__ w,
                                                const float* __restrict__ bias,
                                                float* __restrict__ out) {
    __shared__ float prof[NBINS];
    __shared__ float smn, smx, ssum;
    int b = blockIdx.x;
    int t = threadIdx.x;
    if (t < NBINS) prof[t] = tbin[b * NBINS + t] / (nr[t] + 1e-10f);
    __syncthreads();
    if (t == 0) {
        float mn = prof[1], mx = prof[1];
        for (int i = 2; i <= 179; ++i) {
            float p = prof[i];
            mn = fminf(mn, p);
            mx = fmaxf(mx, p);
        }
        smn = mn; smx = mx; ssum = 0.0f;
    }
    __syncthreads();
    if (t < 90) {
        float denom = smx - smn;
        float v = (prof[90 + t] - smn) / denom;
        if (v != v) v = 0.0f;
        atomicAdd(&ssum, v * w[t]);
    }
    __syncthreads();
    if (t == 0) out[b] = ssum + bias[0];
}

// ---------------------------------------------------------------------------
extern "C" void kernel_launch(void* const* d_in, const int* in_sizes, int n_in,
                              void* d_out, int out_size, void* d_ws, size_t ws_size,
                              hipStream_t stream) {
    const float* x = (const float*)d_in[0];     // (128,3,256,256)
    const float* w = (const float*)d_in[1];     // (1,90)
    const float* bias = (const float*)d_in[2];  // (1,)
    float* out = (float*)d_out;                 // (128,1)

    float* M_re = (float*)d_ws;                    // 65536 f
    float* M_im = M_re + 65536;                    // 65536 f
    u16* A1 = (u16*)(M_im + 65536);                // 512*256 = 131072 u16
    u16* G = A1 + 131072;                          // 128*65536 u16
    u16* Tt_re = G + (size_t)NB * 65536;           // 128*65536 u16
    u16* Tt_im = Tt_re + (size_t)NB * 65536;       // 128*65536 u16
    float* tbin = (float*)(Tt_im + (size_t)NB * 65536);
    float* nr = tbin + NB * NBINS;

    hipMemsetAsync(tbin, 0, NB * NBINS * sizeof(float), stream);

    build_M<<<256, 256, 0, stream>>>(M_re, M_im, A1);
    gray_k<<<8192, 256, 0, stream>>>(x, G);
    count_nr<<<1, 256, 0, stream>>>(nr);

    s1<<<dim3(2, 4, NB), 256, 0, stream>>>(A1, G, Tt_re, Tt_im);
    s2<<<dim3(4, 2, NB), 256, 0, stream>>>(A1, Tt_re, Tt_im, tbin);
    row128<<<NB, 256, 0, stream>>>(M_re, Tt_re, Tt_im, tbin);

    finalize<<<NB, 192, 0, stream>>>(tbin, nr, w, bias, out);
}

// Round 4
// 250.879 us; speedup vs baseline: 2.2530x; 1.3270x over previous
//
#include <hip/hip_runtime.h>
#include <math.h>

#define NBINS 182
#define NB 128   // batch

typedef unsigned short u16;
typedef __attribute__((ext_vector_type(8))) short short8;   // 8 bf16 (4 VGPRs)
typedef __attribute__((ext_vector_type(4))) float f32x4;    // MFMA accumulator

__device__ __forceinline__ u16 f2bf(float f) {
    union { float f; unsigned u; } v; v.f = f;
    unsigned r = v.u + 0x7FFF + ((v.u >> 16) & 1);   // RNE
    return (u16)(r >> 16);
}
__device__ __forceinline__ float bf2f(u16 u) {
    union { unsigned u; float f; } v; v.u = ((unsigned)u) << 16;
    return v.f;
}
__device__ __forceinline__ short8 negbf(short8 v) {
    short8 r;
#pragma unroll
    for (int i = 0; i < 8; ++i) r[i] = v[i] ^ (short)0x8000;
    return r;
}

// ---------------------------------------------------------------------------
// Build M = F_dft @ C_dct (256x256 complex), fp64 accum -> fp32 + bf16 copies.
// A1 (512x256 bf16): rows 0..255 = M_re, rows 256..511 = M_im.
// ---------------------------------------------------------------------------
__global__ __launch_bounds__(256) void build_M(float* __restrict__ M_re,
                                               float* __restrict__ M_im,
                                               u16* __restrict__ A1) {
    __shared__ double ctab[1024];
    __shared__ double stab[1024];
    int t = threadIdx.x;
    for (int i = t; i < 1024; i += 256) {
        double a = 3.14159265358979323846 * (double)i / 512.0;
        ctab[i] = cos(a);
        stab[i] = sin(a);
    }
    __syncthreads();
    int j = blockIdx.x;
    int w = t;
    double re = 0.0, im = 0.0;
    int tw = 2 * w + 1;
    for (int k = 0; k < 256; ++k) {
        int e = (4 * j * k) & 1023;
        int m = (tw * k) & 1023;
        double cw = 2.0 * ctab[m];
        re += ctab[e] * cw;
        im -= stab[e] * cw;
    }
    M_re[j * 256 + w] = (float)re;
    M_im[j * 256 + w] = (float)im;
    A1[j * 256 + w] = f2bf((float)re);
    A1[(j + 256) * 256 + w] = f2bf((float)im);
}

// ---------------------------------------------------------------------------
__device__ __forceinline__ int radial_bin(int dx, int dy) {
    int d2 = dx * dx + dy * dy;
    int bin = (int)sqrtf((float)d2);
    while ((bin + 1) * (bin + 1) <= d2) ++bin;
    while (bin * bin > d2) --bin;
    return bin;
}

// ---------------------------------------------------------------------------
// nr[bin]: 256 blocks (one per row), LDS bins, one global atomic per bin.
// Was: single block, 65536 serialized LDS-atomic iterations -> 93 us.
// Counts are integer-exact in fp32; order-independent.
// ---------------------------------------------------------------------------
__global__ __launch_bounds__(256) void count_nr(float* __restrict__ nr) {
    __shared__ float s[NBINS];
    int t = threadIdx.x;
    int i = blockIdx.x;
    if (t < NBINS) s[t] = 0.0f;
    __syncthreads();
    int bin = radial_bin(t - 128, i - 128);
    atomicAdd(&s[bin], 1.0f);
    __syncthreads();
    if (t < NBINS && s[t] != 0.0f) atomicAdd(&nr[t], s[t]);
}

// ---------------------------------------------------------------------------
// Gray conversion: G[b][h][w] = luma(x), bf16.
// ---------------------------------------------------------------------------
__global__ __launch_bounds__(256) void gray_k(const float* __restrict__ x,
                                              u16* __restrict__ G) {
    int idx = (blockIdx.x * 256 + threadIdx.x) * 4;   // 4 pixels; 8388608 total
    int b = idx >> 16;
    int rem = idx & 65535;
    const float* p = x + (size_t)b * 196608 + rem;
    float4 r = *(const float4*)p;
    float4 g = *(const float4*)(p + 65536);
    float4 bl = *(const float4*)(p + 131072);
    float g0 = 0.2989f * r.x + 0.587f * g.x + 0.114f * bl.x;
    float g1 = 0.2989f * r.y + 0.587f * g.y + 0.114f * bl.y;
    float g2 = 0.2989f * r.z + 0.587f * g.z + 0.114f * bl.z;
    float g3 = 0.2989f * r.w + 0.587f * g.w + 0.114f * bl.w;
    uint2 o;
    o.x = (unsigned)f2bf(g0) | ((unsigned)f2bf(g1) << 16);
    o.y = (unsigned)f2bf(g2) | ((unsigned)f2bf(g3) << 16);
    *(uint2*)(G + idx) = o;
}

// ---------------------------------------------------------------------------
// Stage 1 (MFMA): C[r][h] = sum_w A1[r,w] * G[b,h,w]   (gemm_bt)
// r in [0,512): r<256 -> Tt_re row r, else Tt_im row r-256. Output bf16.
// Block: 128x128 tile, 256 thr, wave = 64x64 (4x4 of 16x16x32). K=256, BK=32.
// ---------------------------------------------------------------------------
__global__ __launch_bounds__(256) void s1(const u16* __restrict__ A1,
                                          const u16* __restrict__ G,
                                          u16* __restrict__ Tt_re,
                                          u16* __restrict__ Tt_im) {
    __shared__ u16 As[128 * 40];   // row stride 40 (16B-aligned, conflict-free)
    __shared__ u16 Bs[128 * 40];
    int b = blockIdx.z;
    int r0 = blockIdx.y * 128;    // 0,128,256,384
    int h0 = blockIdx.x * 128;    // 0,128
    int t = threadIdx.x;
    int lane = t & 63, wv = t >> 6;
    int wr = (wv >> 1) * 64;      // wave row origin in block
    int wc = (wv & 1) * 64;       // wave col origin
    int fr = lane & 15;
    int fk = (lane >> 4) << 3;    // 0,8,16,24

    f32x4 acc[4][4];
#pragma unroll
    for (int i = 0; i < 4; ++i)
#pragma unroll
        for (int j = 0; j < 4; ++j) acc[i][j] = (f32x4){0.f, 0.f, 0.f, 0.f};

    const u16* Ap = A1 + (size_t)r0 * 256;
    const u16* Gp = G + (size_t)b * 65536 + (size_t)h0 * 256;

    for (int kk = 0; kk < 256; kk += 32) {
#pragma unroll
        for (int c = t; c < 512; c += 256) {   // 128 rows x 4 chunks of 8 bf16
            int row = c >> 2, off = (c & 3) << 3;
            *(uint4*)&As[row * 40 + off] =
                *(const uint4*)(Ap + (size_t)row * 256 + kk + off);
            *(uint4*)&Bs[row * 40 + off] =
                *(const uint4*)(Gp + (size_t)row * 256 + kk + off);
        }
        __syncthreads();
        short8 af[4], bfr[4];
#pragma unroll
        for (int i = 0; i < 4; ++i)
            af[i] = *(const short8*)&As[(wr + i * 16 + fr) * 40 + fk];
#pragma unroll
        for (int j = 0; j < 4; ++j)
            bfr[j] = *(const short8*)&Bs[(wc + j * 16 + fr) * 40 + fk];
#pragma unroll
        for (int i = 0; i < 4; ++i)
#pragma unroll
            for (int j = 0; j < 4; ++j)
                acc[i][j] = __builtin_amdgcn_mfma_f32_16x16x32_bf16(
                    af[i], bfr[j], acc[i][j], 0, 0, 0);
        __syncthreads();
    }

    u16* dst = ((r0 < 256) ? Tt_re : Tt_im) + (size_t)b * 65536
             + (size_t)(r0 & 255) * 256;
    int rq = (lane >> 4) << 2;
#pragma unroll
    for (int i = 0; i < 4; ++i)
#pragma unroll
        for (int j = 0; j < 4; ++j) {
            int col = h0 + wc + j * 16 + fr;
#pragma unroll
            for (int reg = 0; reg < 4; ++reg) {
                int row = wr + i * 16 + rq + reg;
                dst[(size_t)row * 256 + col] = f2bf(acc[i][j][reg]);
            }
        }
}

// ---------------------------------------------------------------------------
// Stage 2 (MFMA, complex): F[u][j] = sum_h (M_re+iM_im)[u,h] * Tt[j,h]
// u in [0,128) (Hermitian, weight 2 for u>0), j in [0,256).
// Block: 64x64 tile, 4 waves of 32x32 (2x2 of 16x16x32, re+im accumulators).
// Fused log-mag / fftshift / radial-bin epilogue.
// ---------------------------------------------------------------------------
__global__ __launch_bounds__(256) void s2(const u16* __restrict__ A1,
                                          const u16* __restrict__ Tt_re,
                                          const u16* __restrict__ Tt_im,
                                          float* __restrict__ tbin) {
    __shared__ u16 Ar[64 * 40], Ai[64 * 40], Br[64 * 40], Bi[64 * 40];
    __shared__ float sbins[NBINS];
    int b = blockIdx.z;
    int u0 = blockIdx.y * 64;    // 0,64
    int j0 = blockIdx.x * 64;    // 0,64,128,192
    int t = threadIdx.x;
    int lane = t & 63, wv = t >> 6;
    int wu = (wv >> 1) * 32;
    int wj = (wv & 1) * 32;
    int fr = lane & 15;
    int fk = (lane >> 4) << 3;

    for (int i = t; i < NBINS; i += 256) sbins[i] = 0.0f;

    f32x4 accr[2][2], acci[2][2];
#pragma unroll
    for (int i = 0; i < 2; ++i)
#pragma unroll
        for (int j = 0; j < 2; ++j) {
            accr[i][j] = (f32x4){0.f, 0.f, 0.f, 0.f};
            acci[i][j] = (f32x4){0.f, 0.f, 0.f, 0.f};
        }

    const u16* Apr = A1 + (size_t)u0 * 256;            // M_re rows u
    const u16* Api = A1 + (size_t)(256 + u0) * 256;    // M_im rows u
    const u16* Tr = Tt_re + (size_t)b * 65536 + (size_t)j0 * 256;
    const u16* Ti = Tt_im + (size_t)b * 65536 + (size_t)j0 * 256;

    int lrow = t >> 2, loff = (t & 3) << 3;   // 64 rows x 4 chunks

    for (int kk = 0; kk < 256; kk += 32) {
        *(uint4*)&Ar[lrow * 40 + loff] =
            *(const uint4*)(Apr + (size_t)lrow * 256 + kk + loff);
        *(uint4*)&Ai[lrow * 40 + loff] =
            *(const uint4*)(Api + (size_t)lrow * 256 + kk + loff);
        *(uint4*)&Br[lrow * 40 + loff] =
            *(const uint4*)(Tr + (size_t)lrow * 256 + kk + loff);
        *(uint4*)&Bi[lrow * 40 + loff] =
            *(const uint4*)(Ti + (size_t)lrow * 256 + kk + loff);
        __syncthreads();
        short8 arf[2], aif[2], naif[2], brf[2], bif[2];
#pragma unroll
        for (int i = 0; i < 2; ++i) {
            arf[i] = *(const short8*)&Ar[(wu + i * 16 + fr) * 40 + fk];
            aif[i] = *(const short8*)&Ai[(wu + i * 16 + fr) * 40 + fk];
            naif[i] = negbf(aif[i]);
        }
#pragma unroll
        for (int j = 0; j < 2; ++j) {
            brf[j] = *(const short8*)&Br[(wj + j * 16 + fr) * 40 + fk];
            bif[j] = *(const short8*)&Bi[(wj + j * 16 + fr) * 40 + fk];
        }
#pragma unroll
        for (int i = 0; i < 2; ++i)
#pragma unroll
            for (int j = 0; j < 2; ++j) {
                accr[i][j] = __builtin_amdgcn_mfma_f32_16x16x32_bf16(
                    arf[i], brf[j], accr[i][j], 0, 0, 0);
                accr[i][j] = __builtin_amdgcn_mfma_f32_16x16x32_bf16(
                    naif[i], bif[j], accr[i][j], 0, 0, 0);
                acci[i][j] = __builtin_amdgcn_mfma_f32_16x16x32_bf16(
                    arf[i], bif[j], acci[i][j], 0, 0, 0);
                acci[i][j] = __builtin_amdgcn_mfma_f32_16x16x32_bf16(
                    aif[i], brf[j], acci[i][j], 0, 0, 0);
            }
        __syncthreads();
    }

    int rq = (lane >> 4) << 2;
#pragma unroll
    for (int i = 0; i < 2; ++i)
#pragma unroll
        for (int j = 0; j < 2; ++j) {
            int v = j0 + wj + j * 16 + fr;
            int dx = (v < 128) ? v : v - 256;
#pragma unroll
            for (int reg = 0; reg < 4; ++reg) {
                int u = u0 + wu + i * 16 + rq + reg;   // 0..127
                int dy = u;
                float wrow = (u == 0) ? 1.0f : 2.0f;
                int bin = radial_bin(dx, dy);
                float re = accr[i][j][reg] + 1e-8f;
                float im = acci[i][j][reg] + 1e-8f;
                float mag = logf(sqrtf(re * re + im * im + 1e-10f) + 1e-10f);
                atomicAdd(&sbins[bin], wrow * mag);
            }
        }
    __syncthreads();
    for (int i = t; i < NBINS; i += 256)
        atomicAdd(&tbin[b * NBINS + i], sbins[i]);
}

// ---------------------------------------------------------------------------
// Row 128 of F: F[128,j] = sum_h M_re[128,h] * Tt[j,h], j = 0..128.
// ---------------------------------------------------------------------------
__global__ __launch_bounds__(256) void row128(const float* __restrict__ M_re,
                                              const u16* __restrict__ Tt_re,
                                              const u16* __restrict__ Tt_im,
                                              float* __restrict__ tbin) {
    __shared__ float sM[256];
    int b = blockIdx.x;
    int t = threadIdx.x;
    sM[t] = M_re[128 * 256 + t];
    __syncthreads();
    if (t > 128) return;
    const u16* pr = Tt_re + (size_t)b * 65536 + (size_t)t * 256;
    const u16* pi = Tt_im + (size_t)b * 65536 + (size_t)t * 256;
    float re = 0.0f, im = 0.0f;
    for (int h = 0; h < 256; h += 8) {
        uint4 vr = *(const uint4*)(pr + h);
        uint4 vi = *(const uint4*)(pi + h);
        unsigned wr[4] = {vr.x, vr.y, vr.z, vr.w};
        unsigned wi[4] = {vi.x, vi.y, vi.z, vi.w};
#pragma unroll
        for (int q = 0; q < 4; ++q) {
            re = fmaf(sM[h + 2 * q], bf2f((u16)(wr[q] & 0xffff)), re);
            re = fmaf(sM[h + 2 * q + 1], bf2f((u16)(wr[q] >> 16)), re);
            im = fmaf(sM[h + 2 * q], bf2f((u16)(wi[q] & 0xffff)), im);
            im = fmaf(sM[h + 2 * q + 1], bf2f((u16)(wi[q] >> 16)), im);
        }
    }
    re += 1e-8f; im += 1e-8f;
    float mag = logf(sqrtf(re * re + im * im + 1e-10f) + 1e-10f);
    float wj = (t == 0 || t == 128) ? 1.0f : 2.0f;
    int dx = (t < 128) ? t : t - 256;
    int bin = radial_bin(dx, -128);
    atomicAdd(&tbin[b * NBINS + bin], wj * mag);
}

// ---------------------------------------------------------------------------
__global__ __launch_bounds__(192) void finalize(const float* __restrict__ tbin,
                                                const float* __restrict__ nr,
                                                const float* __restrict__ w,
                                                const float* __restrict__ bias,
                                                float* __restrict__ out) {
    __shared__ float prof[NBINS];
    __shared__ float smn, smx, ssum;
    int b = blockIdx.x;
    int t = threadIdx.x;
    if (t < NBINS) prof[t] = tbin[b * NBINS + t] / (nr[t] + 1e-10f);
    __syncthreads();
    if (t == 0) {
        float mn = prof[1], mx = prof[1];
        for (int i = 2; i <= 179; ++i) {
            float p = prof[i];
            mn = fminf(mn, p);
            mx = fmaxf(mx, p);
        }
        smn = mn; smx = mx; ssum = 0.0f;
    }
    __syncthreads();
    if (t < 90) {
        float denom = smx - smn;
        float v = (prof[90 + t] - smn) / denom;
        if (v != v) v = 0.0f;
        atomicAdd(&ssum, v * w[t]);
    }
    __syncthreads();
    if (t == 0) out[b] = ssum + bias[0];
}

// ---------------------------------------------------------------------------
extern "C" void kernel_launch(void* const* d_in, const int* in_sizes, int n_in,
                              void* d_out, int out_size, void* d_ws, size_t ws_size,
                              hipStream_t stream) {
    const float* x = (const float*)d_in[0];     // (128,3,256,256)
    const float* w = (const float*)d_in[1];     // (1,90)
    const float* bias = (const float*)d_in[2];  // (1,)
    float* out = (float*)d_out;                 // (128,1)

    float* M_re = (float*)d_ws;                    // 65536 f
    float* M_im = M_re + 65536;                    // 65536 f
    u16* A1 = (u16*)(M_im + 65536);                // 512*256 = 131072 u16
    u16* G = A1 + 131072;                          // 128*65536 u16
    u16* Tt_re = G + (size_t)NB * 65536;           // 128*65536 u16
    u16* Tt_im = Tt_re + (size_t)NB * 65536;       // 128*65536 u16
    float* tbin = (float*)(Tt_im + (size_t)NB * 65536);
    float* nr = tbin + NB * NBINS;                 // contiguous after tbin

    // zero tbin AND nr (nr is now atomically accumulated)
    hipMemsetAsync(tbin, 0, (NB * NBINS + NBINS) * sizeof(float), stream);

    build_M<<<256, 256, 0, stream>>>(M_re, M_im, A1);
    gray_k<<<8192, 256, 0, stream>>>(x, G);
    count_nr<<<256, 256, 0, stream>>>(nr);

    s1<<<dim3(2, 4, NB), 256, 0, stream>>>(A1, G, Tt_re, Tt_im);
    s2<<<dim3(4, 2, NB), 256, 0, stream>>>(A1, Tt_re, Tt_im, tbin);
    row128<<<NB, 256, 0, stream>>>(M_re, Tt_re, Tt_im, tbin);

    finalize<<<NB, 192, 0, stream>>>(tbin, nr, w, bias, out);
}

// Round 5
// 248.990 us; speedup vs baseline: 2.2701x; 1.0076x over previous
//
#include <hip/hip_runtime.h>
#include <math.h>

#define NBINS 182
#define NB 128   // batch

typedef unsigned short u16;
typedef __attribute__((ext_vector_type(8))) short short8;   // 8 bf16 (4 VGPRs)
typedef __attribute__((ext_vector_type(4))) float f32x4;    // MFMA accumulator

__device__ __forceinline__ u16 f2bf(float f) {
    union { float f; unsigned u; } v; v.f = f;
    unsigned r = v.u + 0x7FFF + ((v.u >> 16) & 1);   // RNE
    return (u16)(r >> 16);
}
__device__ __forceinline__ float bf2f(u16 u) {
    union { unsigned u; float f; } v; v.u = ((unsigned)u) << 16;
    return v.f;
}
__device__ __forceinline__ short8 negbf(short8 v) {
    short8 r;
#pragma unroll
    for (int i = 0; i < 8; ++i) r[i] = v[i] ^ (short)0x8000;
    return r;
}

__device__ __forceinline__ int radial_bin(int dx, int dy) {
    int d2 = dx * dx + dy * dy;
    int bin = (int)sqrtf((float)d2);
    while ((bin + 1) * (bin + 1) <= d2) ++bin;
    while (bin * bin > d2) --bin;
    return bin;
}

// ---------------------------------------------------------------------------
// prep: one launch doing 4 independent jobs, selected by block range.
//   [0,8192)      gray:   G[b][h][w] = luma(x), bf16
//   [8192,8448)   build_M row j:  M = F_dft @ C_dct (fp64 accum)
//   [8448,8704)   nr partial: per-row radial histogram -> nrpart[row][bin]
//   [8704,8736)   zero tbin
// ---------------------------------------------------------------------------
__global__ __launch_bounds__(256) void prep(const float* __restrict__ x,
                                            u16* __restrict__ G,
                                            float* __restrict__ M_re,
                                            float* __restrict__ M_im,
                                            u16* __restrict__ A1,
                                            float* __restrict__ nrpart,
                                            float* __restrict__ tbin) {
    __shared__ double ctab[1024];
    __shared__ double stab[1024];
    __shared__ float s[NBINS];
    int blk = blockIdx.x;
    int t = threadIdx.x;

    if (blk < 8192) {            // ---- gray ----
        int idx = (blk * 256 + t) * 4;
        int b = idx >> 16;
        int rem = idx & 65535;
        const float* p = x + (size_t)b * 196608 + rem;
        float4 r = *(const float4*)p;
        float4 g = *(const float4*)(p + 65536);
        float4 bl = *(const float4*)(p + 131072);
        float g0 = 0.2989f * r.x + 0.587f * g.x + 0.114f * bl.x;
        float g1 = 0.2989f * r.y + 0.587f * g.y + 0.114f * bl.y;
        float g2 = 0.2989f * r.z + 0.587f * g.z + 0.114f * bl.z;
        float g3 = 0.2989f * r.w + 0.587f * g.w + 0.114f * bl.w;
        uint2 o;
        o.x = (unsigned)f2bf(g0) | ((unsigned)f2bf(g1) << 16);
        o.y = (unsigned)f2bf(g2) | ((unsigned)f2bf(g3) << 16);
        *(uint2*)(G + idx) = o;
    } else if (blk < 8448) {     // ---- build_M ----
        for (int i = t; i < 1024; i += 256) {
            double a = 3.14159265358979323846 * (double)i / 512.0;
            ctab[i] = cos(a);
            stab[i] = sin(a);
        }
        __syncthreads();
        int j = blk - 8192;
        int w = t;
        double re = 0.0, im = 0.0;
        int tw = 2 * w + 1;
        for (int k = 0; k < 256; ++k) {
            int e = (4 * j * k) & 1023;
            int m = (tw * k) & 1023;
            double cw = 2.0 * ctab[m];
            re += ctab[e] * cw;
            im -= stab[e] * cw;
        }
        M_re[j * 256 + w] = (float)re;
        M_im[j * 256 + w] = (float)im;
        A1[j * 256 + w] = f2bf((float)re);
        A1[(j + 256) * 256 + w] = f2bf((float)im);
    } else if (blk < 8704) {     // ---- nr partial histogram, row i ----
        int i = blk - 8448;
        if (t < NBINS) s[t] = 0.0f;
        __syncthreads();
        int bin = radial_bin(t - 128, i - 128);
        atomicAdd(&s[bin], 1.0f);
        __syncthreads();
        if (t < NBINS) nrpart[i * NBINS + t] = s[t];   // full row incl. zeros
    } else {                     // ---- zero tbin ----
        int idx = (blk - 8704) * 256 + t;
        for (int i = idx; i < NB * NBINS; i += 32 * 256) tbin[i] = 0.0f;
    }
}

// ---------------------------------------------------------------------------
// Stage 1 (MFMA): C[r][h] = sum_w A1[r,w] * G[b,h,w]   (gemm_bt)
// r in [0,512): r<256 -> Tt_re row r, else Tt_im row r-256. Output bf16.
// Block: 128x128 tile, 256 thr, wave = 64x64 (4x4 of 16x16x32). K=256, BK=32.
// ---------------------------------------------------------------------------
__global__ __launch_bounds__(256) void s1(const u16* __restrict__ A1,
                                          const u16* __restrict__ G,
                                          u16* __restrict__ Tt_re,
                                          u16* __restrict__ Tt_im) {
    __shared__ u16 As[128 * 40];   // row stride 40 (16B-aligned, conflict-free)
    __shared__ u16 Bs[128 * 40];
    int b = blockIdx.z;
    int r0 = blockIdx.y * 128;    // 0,128,256,384
    int h0 = blockIdx.x * 128;    // 0,128
    int t = threadIdx.x;
    int lane = t & 63, wv = t >> 6;
    int wr = (wv >> 1) * 64;
    int wc = (wv & 1) * 64;
    int fr = lane & 15;
    int fk = (lane >> 4) << 3;

    f32x4 acc[4][4];
#pragma unroll
    for (int i = 0; i < 4; ++i)
#pragma unroll
        for (int j = 0; j < 4; ++j) acc[i][j] = (f32x4){0.f, 0.f, 0.f, 0.f};

    const u16* Ap = A1 + (size_t)r0 * 256;
    const u16* Gp = G + (size_t)b * 65536 + (size_t)h0 * 256;

    for (int kk = 0; kk < 256; kk += 32) {
#pragma unroll
        for (int c = t; c < 512; c += 256) {
            int row = c >> 2, off = (c & 3) << 3;
            *(uint4*)&As[row * 40 + off] =
                *(const uint4*)(Ap + (size_t)row * 256 + kk + off);
            *(uint4*)&Bs[row * 40 + off] =
                *(const uint4*)(Gp + (size_t)row * 256 + kk + off);
        }
        __syncthreads();
        short8 af[4], bfr[4];
#pragma unroll
        for (int i = 0; i < 4; ++i)
            af[i] = *(const short8*)&As[(wr + i * 16 + fr) * 40 + fk];
#pragma unroll
        for (int j = 0; j < 4; ++j)
            bfr[j] = *(const short8*)&Bs[(wc + j * 16 + fr) * 40 + fk];
#pragma unroll
        for (int i = 0; i < 4; ++i)
#pragma unroll
            for (int j = 0; j < 4; ++j)
                acc[i][j] = __builtin_amdgcn_mfma_f32_16x16x32_bf16(
                    af[i], bfr[j], acc[i][j], 0, 0, 0);
        __syncthreads();
    }

    u16* dst = ((r0 < 256) ? Tt_re : Tt_im) + (size_t)b * 65536
             + (size_t)(r0 & 255) * 256;
    int rq = (lane >> 4) << 2;
#pragma unroll
    for (int i = 0; i < 4; ++i)
#pragma unroll
        for (int j = 0; j < 4; ++j) {
            int col = h0 + wc + j * 16 + fr;
#pragma unroll
            for (int reg = 0; reg < 4; ++reg) {
                int row = wr + i * 16 + rq + reg;
                dst[(size_t)row * 256 + col] = f2bf(acc[i][j][reg]);
            }
        }
}

// ---------------------------------------------------------------------------
// s2f: fused stage-2 GEMM (blocks [0,1024)) + row128 (blocks [1024,1152)).
// s2: F[u][j] = sum_h (M_re+iM_im)[u,h]*Tt[j,h], u in [0,128), Hermitian w=2.
// row128: F[128,j] = sum_h M_re[128,h]*Tt[j,h], j=0..128.
// Both feed fused log-mag/fftshift/radial-bin into tbin atomics.
// ---------------------------------------------------------------------------
__global__ __launch_bounds__(256) void s2f(const u16* __restrict__ A1,
                                           const float* __restrict__ M_re,
                                           const u16* __restrict__ Tt_re,
                                           const u16* __restrict__ Tt_im,
                                           float* __restrict__ tbin) {
    __shared__ u16 Ar[64 * 40], Ai[64 * 40], Br[64 * 40], Bi[64 * 40];
    __shared__ float sbins[NBINS];
    __shared__ float sM[256];
    int blk = blockIdx.x;
    int t = threadIdx.x;

    if (blk >= 1024) {           // ---- row128 ----
        int b = blk - 1024;
        sM[t] = M_re[128 * 256 + t];
        __syncthreads();
        if (t > 128) return;
        const u16* pr = Tt_re + (size_t)b * 65536 + (size_t)t * 256;
        const u16* pi = Tt_im + (size_t)b * 65536 + (size_t)t * 256;
        float re = 0.0f, im = 0.0f;
        for (int h = 0; h < 256; h += 8) {
            uint4 vr = *(const uint4*)(pr + h);
            uint4 vi = *(const uint4*)(pi + h);
            unsigned wr[4] = {vr.x, vr.y, vr.z, vr.w};
            unsigned wi[4] = {vi.x, vi.y, vi.z, vi.w};
#pragma unroll
            for (int q = 0; q < 4; ++q) {
                re = fmaf(sM[h + 2 * q], bf2f((u16)(wr[q] & 0xffff)), re);
                re = fmaf(sM[h + 2 * q + 1], bf2f((u16)(wr[q] >> 16)), re);
                im = fmaf(sM[h + 2 * q], bf2f((u16)(wi[q] & 0xffff)), im);
                im = fmaf(sM[h + 2 * q + 1], bf2f((u16)(wi[q] >> 16)), im);
            }
        }
        re += 1e-8f; im += 1e-8f;
        float mag = logf(sqrtf(re * re + im * im + 1e-10f) + 1e-10f);
        float wj = (t == 0 || t == 128) ? 1.0f : 2.0f;
        int dx = (t < 128) ? t : t - 256;
        int bin = radial_bin(dx, -128);
        atomicAdd(&tbin[b * NBINS + bin], wj * mag);
        return;
    }

    // ---- s2 GEMM ----
    int b = blk >> 3;
    int u0 = ((blk >> 2) & 1) * 64;
    int j0 = (blk & 3) * 64;
    int lane = t & 63, wv = t >> 6;
    int wu = (wv >> 1) * 32;
    int wj = (wv & 1) * 32;
    int fr = lane & 15;
    int fk = (lane >> 4) << 3;

    for (int i = t; i < NBINS; i += 256) sbins[i] = 0.0f;

    f32x4 accr[2][2], acci[2][2];
#pragma unroll
    for (int i = 0; i < 2; ++i)
#pragma unroll
        for (int j = 0; j < 2; ++j) {
            accr[i][j] = (f32x4){0.f, 0.f, 0.f, 0.f};
            acci[i][j] = (f32x4){0.f, 0.f, 0.f, 0.f};
        }

    const u16* Apr = A1 + (size_t)u0 * 256;
    const u16* Api = A1 + (size_t)(256 + u0) * 256;
    const u16* Tr = Tt_re + (size_t)b * 65536 + (size_t)j0 * 256;
    const u16* Ti = Tt_im + (size_t)b * 65536 + (size_t)j0 * 256;

    int lrow = t >> 2, loff = (t & 3) << 3;

    for (int kk = 0; kk < 256; kk += 32) {
        *(uint4*)&Ar[lrow * 40 + loff] =
            *(const uint4*)(Apr + (size_t)lrow * 256 + kk + loff);
        *(uint4*)&Ai[lrow * 40 + loff] =
            *(const uint4*)(Api + (size_t)lrow * 256 + kk + loff);
        *(uint4*)&Br[lrow * 40 + loff] =
            *(const uint4*)(Tr + (size_t)lrow * 256 + kk + loff);
        *(uint4*)&Bi[lrow * 40 + loff] =
            *(const uint4*)(Ti + (size_t)lrow * 256 + kk + loff);
        __syncthreads();
        short8 arf[2], aif[2], naif[2], brf[2], bif[2];
#pragma unroll
        for (int i = 0; i < 2; ++i) {
            arf[i] = *(const short8*)&Ar[(wu + i * 16 + fr) * 40 + fk];
            aif[i] = *(const short8*)&Ai[(wu + i * 16 + fr) * 40 + fk];
            naif[i] = negbf(aif[i]);
        }
#pragma unroll
        for (int j = 0; j < 2; ++j) {
            brf[j] = *(const short8*)&Br[(wj + j * 16 + fr) * 40 + fk];
            bif[j] = *(const short8*)&Bi[(wj + j * 16 + fr) * 40 + fk];
        }
#pragma unroll
        for (int i = 0; i < 2; ++i)
#pragma unroll
            for (int j = 0; j < 2; ++j) {
                accr[i][j] = __builtin_amdgcn_mfma_f32_16x16x32_bf16(
                    arf[i], brf[j], accr[i][j], 0, 0, 0);
                accr[i][j] = __builtin_amdgcn_mfma_f32_16x16x32_bf16(
                    naif[i], bif[j], accr[i][j], 0, 0, 0);
                acci[i][j] = __builtin_amdgcn_mfma_f32_16x16x32_bf16(
                    arf[i], bif[j], acci[i][j], 0, 0, 0);
                acci[i][j] = __builtin_amdgcn_mfma_f32_16x16x32_bf16(
                    aif[i], brf[j], acci[i][j], 0, 0, 0);
            }
        __syncthreads();
    }

    int rq = (lane >> 4) << 2;
#pragma unroll
    for (int i = 0; i < 2; ++i)
#pragma unroll
        for (int j = 0; j < 2; ++j) {
            int v = j0 + wj + j * 16 + fr;
            int dx = (v < 128) ? v : v - 256;
#pragma unroll
            for (int reg = 0; reg < 4; ++reg) {
                int u = u0 + wu + i * 16 + rq + reg;   // 0..127
                float wrow = (u == 0) ? 1.0f : 2.0f;
                int bin = radial_bin(dx, u);
                float re = accr[i][j][reg] + 1e-8f;
                float im = acci[i][j][reg] + 1e-8f;
                float mag = logf(sqrtf(re * re + im * im + 1e-10f) + 1e-10f);
                atomicAdd(&sbins[bin], wrow * mag);
            }
        }
    __syncthreads();
    for (int i = t; i < NBINS; i += 256)
        atomicAdd(&tbin[b * NBINS + i], sbins[i]);
}

// ---------------------------------------------------------------------------
// Finalize: nr = column-sum of nrpart; prof = tbin/nr; min-max over 1..179;
// dot bins 90..179 with w.
// ---------------------------------------------------------------------------
__global__ __launch_bounds__(192) void finalize(const float* __restrict__ tbin,
                                                const float* __restrict__ nrpart,
                                                const float* __restrict__ w,
                                                const float* __restrict__ bias,
                                                float* __restrict__ out) {
    __shared__ float prof[NBINS];
    __shared__ float smn, smx, ssum;
    int b = blockIdx.x;
    int t = threadIdx.x;
    if (t < NBINS) {
        float nr = 0.0f;
        for (int i = 0; i < 256; ++i) nr += nrpart[i * NBINS + t];
        prof[t] = tbin[b * NBINS + t] / (nr + 1e-10f);
    }
    __syncthreads();
    if (t == 0) {
        float mn = prof[1], mx = prof[1];
        for (int i = 2; i <= 179; ++i) {
            float p = prof[i];
            mn = fminf(mn, p);
            mx = fmaxf(mx, p);
        }
        smn = mn; smx = mx; ssum = 0.0f;
    }
    __syncthreads();
    if (t < 90) {
        float denom = smx - smn;
        float v = (prof[90 + t] - smn) / denom;
        if (v != v) v = 0.0f;
        atomicAdd(&ssum, v * w[t]);
    }
    __syncthreads();
    if (t == 0) out[b] = ssum + bias[0];
}

// ---------------------------------------------------------------------------
extern "C" void kernel_launch(void* const* d_in, const int* in_sizes, int n_in,
                              void* d_out, int out_size, void* d_ws, size_t ws_size,
                              hipStream_t stream) {
    const float* x = (const float*)d_in[0];     // (128,3,256,256)
    const float* w = (const float*)d_in[1];     // (1,90)
    const float* bias = (const float*)d_in[2];  // (1,)
    float* out = (float*)d_out;                 // (128,1)

    float* M_re = (float*)d_ws;                    // 65536 f
    float* M_im = M_re + 65536;                    // 65536 f
    u16* A1 = (u16*)(M_im + 65536);                // 512*256 u16
    u16* G = A1 + 131072;                          // 128*65536 u16
    u16* Tt_re = G + (size_t)NB * 65536;           // 128*65536 u16
    u16* Tt_im = Tt_re + (size_t)NB * 65536;       // 128*65536 u16
    float* tbin = (float*)(Tt_im + (size_t)NB * 65536);   // NB*NBINS f
    float* nrpart = tbin + NB * NBINS;             // 256*NBINS f

    prep<<<8736, 256, 0, stream>>>(x, G, M_re, M_im, A1, nrpart, tbin);
    s1<<<dim3(2, 4, NB), 256, 0, stream>>>(A1, G, Tt_re, Tt_im);
    s2f<<<1152, 256, 0, stream>>>(A1, M_re, Tt_re, Tt_im, tbin);
    finalize<<<NB, 192, 0, stream>>>(tbin, nrpart, w, bias, out);
}

// Round 6
// 230.116 us; speedup vs baseline: 2.4563x; 1.0820x over previous
//
#include <hip/hip_runtime.h>
#include <math.h>

#define NBINS 182
#define NB 128   // batch

typedef unsigned short u16;
typedef __attribute__((ext_vector_type(8))) short short8;   // 8 bf16 (4 VGPRs)
typedef __attribute__((ext_vector_type(4))) float f32x4;    // MFMA accumulator

__device__ __forceinline__ u16 f2bf(float f) {
    union { float f; unsigned u; } v; v.f = f;
    unsigned r = v.u + 0x7FFF + ((v.u >> 16) & 1);   // RNE
    return (u16)(r >> 16);
}
__device__ __forceinline__ float bf2f(u16 u) {
    union { unsigned u; float f; } v; v.u = ((unsigned)u) << 16;
    return v.f;
}
__device__ __forceinline__ short8 negbf(short8 v) {
    short8 r;
#pragma unroll
    for (int i = 0; i < 8; ++i) r[i] = v[i] ^ (short)0x8000;
    return r;
}

__device__ __forceinline__ int radial_bin(int dx, int dy) {
    int d2 = dx * dx + dy * dy;
    int bin = (int)sqrtf((float)d2);
    while ((bin + 1) * (bin + 1) <= d2) ++bin;
    while (bin * bin > d2) --bin;
    return bin;
}

// ---------------------------------------------------------------------------
// prep: one launch, 4 jobs by block range. Heavy/latency blocks FIRST so they
// overlap the gray stream (they dispatch to CUs before the 1024 gray blocks).
//   [0,256)      build_M row j (fp64 accum -> M fp32 + A1 bf16)
//   [256,512)    nr partial histogram -> nrpart[row][bin]
//   [512,544)    zero tbin
//   [544,1568)   gray grid-stride: G = luma(x) bf16, 8 float4-groups/thread
// ---------------------------------------------------------------------------
__global__ __launch_bounds__(256) void prep(const float* __restrict__ x,
                                            u16* __restrict__ G,
                                            float* __restrict__ M_re,
                                            float* __restrict__ M_im,
                                            u16* __restrict__ A1,
                                            float* __restrict__ nrpart,
                                            float* __restrict__ tbin) {
    __shared__ double ctab[1024];
    __shared__ double stab[1024];
    __shared__ float s[NBINS];
    int blk = blockIdx.x;
    int t = threadIdx.x;

    if (blk < 256) {             // ---- build_M ----
        for (int i = t; i < 1024; i += 256) {
            double a = 3.14159265358979323846 * (double)i / 512.0;
            ctab[i] = cos(a);
            stab[i] = sin(a);
        }
        __syncthreads();
        int j = blk;
        int w = t;
        double re = 0.0, im = 0.0;
        int tw = 2 * w + 1;
        for (int k = 0; k < 256; ++k) {
            int e = (4 * j * k) & 1023;
            int m = (tw * k) & 1023;
            double cw = 2.0 * ctab[m];
            re += ctab[e] * cw;
            im -= stab[e] * cw;
        }
        M_re[j * 256 + w] = (float)re;
        M_im[j * 256 + w] = (float)im;
        A1[j * 256 + w] = f2bf((float)re);
        A1[(j + 256) * 256 + w] = f2bf((float)im);
    } else if (blk < 512) {      // ---- nr partial histogram, row i ----
        int i = blk - 256;
        if (t < NBINS) s[t] = 0.0f;
        __syncthreads();
        int bin = radial_bin(t - 128, i - 128);
        atomicAdd(&s[bin], 1.0f);
        __syncthreads();
        if (t < NBINS) nrpart[i * NBINS + t] = s[t];
    } else if (blk < 544) {      // ---- zero tbin ----
        int idx = (blk - 512) * 256 + t;
        for (int i = idx; i < NB * NBINS; i += 32 * 256) tbin[i] = 0.0f;
    } else {                     // ---- gray, grid-stride ----
        int tid = (blk - 544) * 256 + t;          // 0..262143
        for (int i = tid; i < 2097152; i += 262144) {   // 8 iters
            int idx = i * 4;
            int b = idx >> 16;
            int rem = idx & 65535;
            const float* p = x + (size_t)b * 196608 + rem;
            float4 r = *(const float4*)p;
            float4 g = *(const float4*)(p + 65536);
            float4 bl = *(const float4*)(p + 131072);
            float g0 = 0.2989f * r.x + 0.587f * g.x + 0.114f * bl.x;
            float g1 = 0.2989f * r.y + 0.587f * g.y + 0.114f * bl.y;
            float g2 = 0.2989f * r.z + 0.587f * g.z + 0.114f * bl.z;
            float g3 = 0.2989f * r.w + 0.587f * g.w + 0.114f * bl.w;
            uint2 o;
            o.x = (unsigned)f2bf(g0) | ((unsigned)f2bf(g1) << 16);
            o.y = (unsigned)f2bf(g2) | ((unsigned)f2bf(g3) << 16);
            *(uint2*)(G + idx) = o;
        }
    }
}

// ---------------------------------------------------------------------------
// Stage 1 (MFMA): C[r][h] = sum_w A1[r,w] * G[b,h,w]   (gemm_bt)
// r in [0,512): r<256 -> Tt_re row r, else Tt_im row r-256. Output bf16.
// Block: 128x128 tile, 256 thr, wave = 64x64 (4x4 of 16x16x32). K=256, BK=32.
// ---------------------------------------------------------------------------
__global__ __launch_bounds__(256) void s1(const u16* __restrict__ A1,
                                          const u16* __restrict__ G,
                                          u16* __restrict__ Tt_re,
                                          u16* __restrict__ Tt_im) {
    __shared__ u16 As[128 * 40];   // row stride 40 (16B-aligned, conflict-free)
    __shared__ u16 Bs[128 * 40];
    int b = blockIdx.z;
    int r0 = blockIdx.y * 128;    // 0,128,256,384
    int h0 = blockIdx.x * 128;    // 0,128
    int t = threadIdx.x;
    int lane = t & 63, wv = t >> 6;
    int wr = (wv >> 1) * 64;
    int wc = (wv & 1) * 64;
    int fr = lane & 15;
    int fk = (lane >> 4) << 3;

    f32x4 acc[4][4];
#pragma unroll
    for (int i = 0; i < 4; ++i)
#pragma unroll
        for (int j = 0; j < 4; ++j) acc[i][j] = (f32x4){0.f, 0.f, 0.f, 0.f};

    const u16* Ap = A1 + (size_t)r0 * 256;
    const u16* Gp = G + (size_t)b * 65536 + (size_t)h0 * 256;

    for (int kk = 0; kk < 256; kk += 32) {
#pragma unroll
        for (int c = t; c < 512; c += 256) {
            int row = c >> 2, off = (c & 3) << 3;
            *(uint4*)&As[row * 40 + off] =
                *(const uint4*)(Ap + (size_t)row * 256 + kk + off);
            *(uint4*)&Bs[row * 40 + off] =
                *(const uint4*)(Gp + (size_t)row * 256 + kk + off);
        }
        __syncthreads();
        short8 af[4], bfr[4];
#pragma unroll
        for (int i = 0; i < 4; ++i)
            af[i] = *(const short8*)&As[(wr + i * 16 + fr) * 40 + fk];
#pragma unroll
        for (int j = 0; j < 4; ++j)
            bfr[j] = *(const short8*)&Bs[(wc + j * 16 + fr) * 40 + fk];
#pragma unroll
        for (int i = 0; i < 4; ++i)
#pragma unroll
            for (int j = 0; j < 4; ++j)
                acc[i][j] = __builtin_amdgcn_mfma_f32_16x16x32_bf16(
                    af[i], bfr[j], acc[i][j], 0, 0, 0);
        __syncthreads();
    }

    u16* dst = ((r0 < 256) ? Tt_re : Tt_im) + (size_t)b * 65536
             + (size_t)(r0 & 255) * 256;
    int rq = (lane >> 4) << 2;
#pragma unroll
    for (int i = 0; i < 4; ++i)
#pragma unroll
        for (int j = 0; j < 4; ++j) {
            int col = h0 + wc + j * 16 + fr;
#pragma unroll
            for (int reg = 0; reg < 4; ++reg) {
                int row = wr + i * 16 + rq + reg;
                dst[(size_t)row * 256 + col] = f2bf(acc[i][j][reg]);
            }
        }
}

// ---------------------------------------------------------------------------
// s2f: fused stage-2 GEMM (blocks [0,1024)) + row128 (blocks [1024,1152)).
// s2: F[u][j] = sum_h (M_re+iM_im)[u,h]*Tt[j,h], u in [0,128), Hermitian w=2.
// row128: F[128,j] = sum_h M_re[128,h]*Tt[j,h], j=0..128.
// Both feed fused log-mag/fftshift/radial-bin into tbin atomics.
// ---------------------------------------------------------------------------
__global__ __launch_bounds__(256) void s2f(const u16* __restrict__ A1,
                                           const float* __restrict__ M_re,
                                           const u16* __restrict__ Tt_re,
                                           const u16* __restrict__ Tt_im,
                                           float* __restrict__ tbin) {
    __shared__ u16 Ar[64 * 40], Ai[64 * 40], Br[64 * 40], Bi[64 * 40];
    __shared__ float sbins[NBINS];
    __shared__ float sM[256];
    int blk = blockIdx.x;
    int t = threadIdx.x;

    if (blk >= 1024) {           // ---- row128 ----
        int b = blk - 1024;
        sM[t] = M_re[128 * 256 + t];
        __syncthreads();
        if (t > 128) return;
        const u16* pr = Tt_re + (size_t)b * 65536 + (size_t)t * 256;
        const u16* pi = Tt_im + (size_t)b * 65536 + (size_t)t * 256;
        float re = 0.0f, im = 0.0f;
        for (int h = 0; h < 256; h += 8) {
            uint4 vr = *(const uint4*)(pr + h);
            uint4 vi = *(const uint4*)(pi + h);
            unsigned wr[4] = {vr.x, vr.y, vr.z, vr.w};
            unsigned wi[4] = {vi.x, vi.y, vi.z, vi.w};
#pragma unroll
            for (int q = 0; q < 4; ++q) {
                re = fmaf(sM[h + 2 * q], bf2f((u16)(wr[q] & 0xffff)), re);
                re = fmaf(sM[h + 2 * q + 1], bf2f((u16)(wr[q] >> 16)), re);
                im = fmaf(sM[h + 2 * q], bf2f((u16)(wi[q] & 0xffff)), im);
                im = fmaf(sM[h + 2 * q + 1], bf2f((u16)(wi[q] >> 16)), im);
            }
        }
        re += 1e-8f; im += 1e-8f;
        float mag = logf(sqrtf(re * re + im * im + 1e-10f) + 1e-10f);
        float wj = (t == 0 || t == 128) ? 1.0f : 2.0f;
        int dx = (t < 128) ? t : t - 256;
        int bin = radial_bin(dx, -128);
        atomicAdd(&tbin[b * NBINS + bin], wj * mag);
        return;
    }

    // ---- s2 GEMM ----
    int b = blk >> 3;
    int u0 = ((blk >> 2) & 1) * 64;
    int j0 = (blk & 3) * 64;
    int lane = t & 63, wv = t >> 6;
    int wu = (wv >> 1) * 32;
    int wj = (wv & 1) * 32;
    int fr = lane & 15;
    int fk = (lane >> 4) << 3;

    for (int i = t; i < NBINS; i += 256) sbins[i] = 0.0f;

    f32x4 accr[2][2], acci[2][2];
#pragma unroll
    for (int i = 0; i < 2; ++i)
#pragma unroll
        for (int j = 0; j < 2; ++j) {
            accr[i][j] = (f32x4){0.f, 0.f, 0.f, 0.f};
            acci[i][j] = (f32x4){0.f, 0.f, 0.f, 0.f};
        }

    const u16* Apr = A1 + (size_t)u0 * 256;
    const u16* Api = A1 + (size_t)(256 + u0) * 256;
    const u16* Tr = Tt_re + (size_t)b * 65536 + (size_t)j0 * 256;
    const u16* Ti = Tt_im + (size_t)b * 65536 + (size_t)j0 * 256;

    int lrow = t >> 2, loff = (t & 3) << 3;

    for (int kk = 0; kk < 256; kk += 32) {
        *(uint4*)&Ar[lrow * 40 + loff] =
            *(const uint4*)(Apr + (size_t)lrow * 256 + kk + loff);
        *(uint4*)&Ai[lrow * 40 + loff] =
            *(const uint4*)(Api + (size_t)lrow * 256 + kk + loff);
        *(uint4*)&Br[lrow * 40 + loff] =
            *(const uint4*)(Tr + (size_t)lrow * 256 + kk + loff);
        *(uint4*)&Bi[lrow * 40 + loff] =
            *(const uint4*)(Ti + (size_t)lrow * 256 + kk + loff);
        __syncthreads();
        short8 arf[2], aif[2], naif[2], brf[2], bif[2];
#pragma unroll
        for (int i = 0; i < 2; ++i) {
            arf[i] = *(const short8*)&Ar[(wu + i * 16 + fr) * 40 + fk];
            aif[i] = *(const short8*)&Ai[(wu + i * 16 + fr) * 40 + fk];
            naif[i] = negbf(aif[i]);
        }
#pragma unroll
        for (int j = 0; j < 2; ++j) {
            brf[j] = *(const short8*)&Br[(wj + j * 16 + fr) * 40 + fk];
            bif[j] = *(const short8*)&Bi[(wj + j * 16 + fr) * 40 + fk];
        }
#pragma unroll
        for (int i = 0; i < 2; ++i)
#pragma unroll
            for (int j = 0; j < 2; ++j) {
                accr[i][j] = __builtin_amdgcn_mfma_f32_16x16x32_bf16(
                    arf[i], brf[j], accr[i][j], 0, 0, 0);
                accr[i][j] = __builtin_amdgcn_mfma_f32_16x16x32_bf16(
                    naif[i], bif[j], accr[i][j], 0, 0, 0);
                acci[i][j] = __builtin_amdgcn_mfma_f32_16x16x32_bf16(
                    arf[i], bif[j], acci[i][j], 0, 0, 0);
                acci[i][j] = __builtin_amdgcn_mfma_f32_16x16x32_bf16(
                    aif[i], brf[j], acci[i][j], 0, 0, 0);
            }
        __syncthreads();
    }

    int rq = (lane >> 4) << 2;
#pragma unroll
    for (int i = 0; i < 2; ++i)
#pragma unroll
        for (int j = 0; j < 2; ++j) {
            int v = j0 + wj + j * 16 + fr;
            int dx = (v < 128) ? v : v - 256;
#pragma unroll
            for (int reg = 0; reg < 4; ++reg) {
                int u = u0 + wu + i * 16 + rq + reg;   // 0..127
                float wrow = (u == 0) ? 1.0f : 2.0f;
                int bin = radial_bin(dx, u);
                float re = accr[i][j][reg] + 1e-8f;
                float im = acci[i][j][reg] + 1e-8f;
                float mag = logf(sqrtf(re * re + im * im + 1e-10f) + 1e-10f);
                atomicAdd(&sbins[bin], wrow * mag);
            }
        }
    __syncthreads();
    for (int i = t; i < NBINS; i += 256)
        atomicAdd(&tbin[b * NBINS + i], sbins[i]);
}

// ---------------------------------------------------------------------------
// Finalize: nr = column-sum of nrpart; prof = tbin/nr; min-max over 1..179;
// dot bins 90..179 with w.
// ---------------------------------------------------------------------------
__global__ __launch_bounds__(192) void finalize(const float* __restrict__ tbin,
                                                const float* __restrict__ nrpart,
                                                const float* __restrict__ w,
                                                const float* __restrict__ bias,
                                                float* __restrict__ out) {
    __shared__ float prof[NBINS];
    __shared__ float smn, smx, ssum;
    int b = blockIdx.x;
    int t = threadIdx.x;
    if (t < NBINS) {
        float nr = 0.0f;
        for (int i = 0; i < 256; ++i) nr += nrpart[i * NBINS + t];
        prof[t] = tbin[b * NBINS + t] / (nr + 1e-10f);
    }
    __syncthreads();
    if (t == 0) {
        float mn = prof[1], mx = prof[1];
        for (int i = 2; i <= 179; ++i) {
            float p = prof[i];
            mn = fminf(mn, p);
            mx = fmaxf(mx, p);
        }
        smn = mn; smx = mx; ssum = 0.0f;
    }
    __syncthreads();
    if (t < 90) {
        float denom = smx - smn;
        float v = (prof[90 + t] - smn) / denom;
        if (v != v) v = 0.0f;
        atomicAdd(&ssum, v * w[t]);
    }
    __syncthreads();
    if (t == 0) out[b] = ssum + bias[0];
}

// ---------------------------------------------------------------------------
extern "C" void kernel_launch(void* const* d_in, const int* in_sizes, int n_in,
                              void* d_out, int out_size, void* d_ws, size_t ws_size,
                              hipStream_t stream) {
    const float* x = (const float*)d_in[0];     // (128,3,256,256)
    const float* w = (const float*)d_in[1];     // (1,90)
    const float* bias = (const float*)d_in[2];  // (1,)
    float* out = (float*)d_out;                 // (128,1)

    float* M_re = (float*)d_ws;                    // 65536 f
    float* M_im = M_re + 65536;                    // 65536 f
    u16* A1 = (u16*)(M_im + 65536);                // 512*256 u16
    u16* G = A1 + 131072;                          // 128*65536 u16
    u16* Tt_re = G + (size_t)NB * 65536;           // 128*65536 u16
    u16* Tt_im = Tt_re + (size_t)NB * 65536;       // 128*65536 u16
    float* tbin = (float*)(Tt_im + (size_t)NB * 65536);   // NB*NBINS f
    float* nrpart = tbin + NB * NBINS;             // 256*NBINS f

    prep<<<1568, 256, 0, stream>>>(x, G, M_re, M_im, A1, nrpart, tbin);
    s1<<<dim3(2, 4, NB), 256, 0, stream>>>(A1, G, Tt_re, Tt_im);
    s2f<<<1152, 256, 0, stream>>>(A1, M_re, Tt_re, Tt_im, tbin);
    finalize<<<NB, 192, 0, stream>>>(tbin, nrpart, w, bias, out);
}